// Round 1
// baseline (1271.467 us; speedup 1.0000x reference)
//
#include <hip/hip_runtime.h>
#include <cmath>

#define B_    2
#define T_    512
#define C_    1024
#define E_    8
#define NTOK  1024
#define NPAIR 2048
#define AH_   1024
#define NH_   8
#define HS_   128

// ---------------- kernel 1: gates, top-2 routing, aux accumulators ----------------
__global__ __launch_bounds__(64) void gate_kernel(
    const float* __restrict__ x, const float* __restrict__ Wg,
    float* __restrict__ gates, float* __restrict__ probs_sum,
    float* __restrict__ frac_cnt, int* __restrict__ bucket_cnt,
    int* __restrict__ buckets)
{
    int token = blockIdx.x;
    int lane  = threadIdx.x;
    const float* xr = x + (size_t)token * C_;
    float acc[E_];
#pragma unroll
    for (int e = 0; e < E_; e++) acc[e] = 0.f;
    for (int c = lane; c < C_; c += 64) {
        float xv = xr[c];
        const float* wr = Wg + c * E_;
#pragma unroll
        for (int e = 0; e < E_; e++) acc[e] += xv * wr[e];
    }
#pragma unroll
    for (int e = 0; e < E_; e++) {
        float v = acc[e];
        v += __shfl_xor(v, 32); v += __shfl_xor(v, 16); v += __shfl_xor(v, 8);
        v += __shfl_xor(v, 4);  v += __shfl_xor(v, 2);  v += __shfl_xor(v, 1);
        acc[e] = v;
    }
    if (lane == 0) {
        int i0 = 0; float v0 = acc[0];
        for (int e = 1; e < E_; e++) if (acc[e] > v0) { v0 = acc[e]; i0 = e; }
        int i1 = -1; float v1 = -3.4e38f;
        for (int e = 0; e < E_; e++) if (e != i0 && acc[e] > v1) { v1 = acc[e]; i1 = e; }
        // gates = softmax([v0, v1]) with v0 >= v1
        float e1  = __expf(v1 - v0);
        float inv = 1.f / (1.f + e1);
        gates[token * 2 + 0] = inv;
        gates[token * 2 + 1] = e1 * inv;
        // probs = softmax over all 8
        float s = 0.f; float pe[E_];
        for (int e = 0; e < E_; e++) { pe[e] = __expf(acc[e] - v0); s += pe[e]; }
        float sinv = 1.f / s;
        for (int e = 0; e < E_; e++) atomicAdd(&probs_sum[e], pe[e] * sinv);
        atomicAdd(&frac_cnt[i0], 1.f);
        atomicAdd(&frac_cnt[i1], 1.f);
        int p0 = atomicAdd(&bucket_cnt[i0], 1);
        buckets[i0 * NPAIR + p0] = token * 2 + 0;
        int p1 = atomicAdd(&bucket_cnt[i1], 1);
        buckets[i1 * NPAIR + p1] = token * 2 + 1;
    }
}

// ---------------- kernel 2: dense K,V projection GEMM ----------------
// grid: (NTOK/64, 2048/64)  block: 256
__global__ __launch_bounds__(256) void kv_gemm(
    const float* __restrict__ x,
    const float* __restrict__ Wk, const float* __restrict__ bk,
    const float* __restrict__ Wv, const float* __restrict__ bv,
    float* __restrict__ kout, float* __restrict__ vout)
{
    __shared__ __align__(16) float As[16][68];
    __shared__ __align__(16) float Bs[16][64];
    int mt = blockIdx.x, nt = blockIdx.y;
    bool isv = (nt >= 16);
    const float* W    = isv ? Wv : Wk;
    const float* bias = isv ? bv : bk;
    int n0 = (isv ? (nt - 16) : nt) * 64;
    int m0 = mt * 64;
    int tid = threadIdx.x;
    int tx = tid & 15, ty = tid >> 4;
    float accum[4][4];
#pragma unroll
    for (int i = 0; i < 4; i++)
#pragma unroll
        for (int j = 0; j < 4; j++) accum[i][j] = 0.f;
    int arow = tid >> 2, acg = tid & 3;       // A loader: 64 rows x 16 k
    int bkk  = tid >> 4, bn  = (tid & 15) * 4; // B loader: 16 k x 64 n
    for (int k0 = 0; k0 < 1024; k0 += 16) {
        float4 av = *(const float4*)&x[(size_t)(m0 + arow) * 1024 + k0 + acg * 4];
        As[acg * 4 + 0][arow] = av.x; As[acg * 4 + 1][arow] = av.y;
        As[acg * 4 + 2][arow] = av.z; As[acg * 4 + 3][arow] = av.w;
        *(float4*)&Bs[bkk][bn] = *(const float4*)&W[(size_t)(k0 + bkk) * 1024 + n0 + bn];
        __syncthreads();
#pragma unroll
        for (int kk = 0; kk < 16; kk++) {
            float a[4], b[4];
            *(float4*)a = *(const float4*)&As[kk][ty * 4];
            *(float4*)b = *(const float4*)&Bs[kk][tx * 4];
#pragma unroll
            for (int i = 0; i < 4; i++)
#pragma unroll
                for (int j = 0; j < 4; j++) accum[i][j] += a[i] * b[j];
        }
        __syncthreads();
    }
    float* outp = isv ? vout : kout;
#pragma unroll
    for (int i = 0; i < 4; i++) {
        int m = m0 + ty * 4 + i;
        int n = n0 + tx * 4;
        float4 r;
        r.x = accum[i][0] + bias[n + 0];
        r.y = accum[i][1] + bias[n + 1];
        r.z = accum[i][2] + bias[n + 2];
        r.w = accum[i][3] + bias[n + 3];
        *(float4*)&outp[(size_t)m * 1024 + n] = r;
    }
}

// ---------------- kernel 3/5: routed (gathered) GEMM ----------------
// Out[pair, n] = sum_k A[rowid >> rowshift, k] * W[e][k][n]
// grid: (E_*32, 16)  block: 256.  K = N = 1024.
__global__ __launch_bounds__(256) void routed_gemm(
    const float* __restrict__ A, const float* __restrict__ Wbase,
    const int* __restrict__ bucket_cnt, const int* __restrict__ buckets,
    int rowshift, float* __restrict__ Out)
{
    int e  = blockIdx.x >> 5;
    int mt = blockIdx.x & 31;
    int nt = blockIdx.y;
    int cnt = bucket_cnt[e];
    if (mt * 64 >= cnt) return;
    __shared__ int rowid[64];
    __shared__ __align__(16) float As[16][68];
    __shared__ __align__(16) float Bs[16][64];
    int tid = threadIdx.x;
    if (tid < 64) {
        int idx = mt * 64 + tid;
        rowid[tid] = buckets[e * NPAIR + (idx < cnt ? idx : cnt - 1)];
    }
    __syncthreads();
    const float* W = Wbase + (size_t)e * 1024 * 1024;
    int n0 = nt * 64;
    int tx = tid & 15, ty = tid >> 4;
    float accum[4][4];
#pragma unroll
    for (int i = 0; i < 4; i++)
#pragma unroll
        for (int j = 0; j < 4; j++) accum[i][j] = 0.f;
    int arow = tid >> 2, acg = tid & 3;
    int bkk  = tid >> 4, bn  = (tid & 15) * 4;
    int asrc = rowid[arow] >> rowshift;
    for (int k0 = 0; k0 < 1024; k0 += 16) {
        float4 av = *(const float4*)&A[(size_t)asrc * 1024 + k0 + acg * 4];
        As[acg * 4 + 0][arow] = av.x; As[acg * 4 + 1][arow] = av.y;
        As[acg * 4 + 2][arow] = av.z; As[acg * 4 + 3][arow] = av.w;
        *(float4*)&Bs[bkk][bn] = *(const float4*)&W[(size_t)(k0 + bkk) * 1024 + n0 + bn];
        __syncthreads();
#pragma unroll
        for (int kk = 0; kk < 16; kk++) {
            float a[4], b[4];
            *(float4*)a = *(const float4*)&As[kk][ty * 4];
            *(float4*)b = *(const float4*)&Bs[kk][tx * 4];
#pragma unroll
            for (int i = 0; i < 4; i++)
#pragma unroll
                for (int j = 0; j < 4; j++) accum[i][j] += a[i] * b[j];
        }
        __syncthreads();
    }
#pragma unroll
    for (int i = 0; i < 4; i++) {
        int gi = mt * 64 + ty * 4 + i;
        if (gi < cnt) {
            int pair = rowid[ty * 4 + i];
            float4 r;
            r.x = accum[i][0]; r.y = accum[i][1]; r.z = accum[i][2]; r.w = accum[i][3];
            *(float4*)&Out[(size_t)pair * 1024 + n0 + tx * 4] = r;
        }
    }
}

// ---------------- kernel 4: stick-breaking attention ----------------
// grid: (32 combos = b*16+slot*8+h, 16 i-tiles)  block: 256
// A[i,j] = sigmoid(s_ij) * prod_{j<l<=i}(1 - sigmoid(s_il)); y_i = sum_j A[i,j] v_j
__global__ __launch_bounds__(256) void attn_kernel(
    const float* __restrict__ q, const float* __restrict__ kmat,
    const float* __restrict__ vmat, const float* __restrict__ gates,
    float* __restrict__ y)
{
    int combo = blockIdx.x;
    int it    = blockIdx.y;
    int b = combo >> 4, slot = (combo >> 3) & 1, h = combo & 7;
    int i0 = it * 32;
    __shared__ __align__(16) float qs[32][128];
    __shared__ float ks[32][129];
    __shared__ __align__(16) float vs[32][128];
    __shared__ float sw[32][33];
    int tid = threadIdx.x;
    // load Q tile (rows i0..i0+31, this b/slot/h)
#pragma unroll
    for (int p = 0; p < 4; p++) {
        int f = tid + 256 * p;           // float4 id over 32*32
        int r = f >> 5, d4 = f & 31;
        *(float4*)&qs[r][d4 * 4] =
            *(const float4*)&q[((size_t)((b * T_ + i0 + r) * 2 + slot)) * 1024 + h * HS_ + d4 * 4];
    }
    float running = 0.f;                 // per scan-thread (tid < 32): running log-survival
    float acc[16];
#pragma unroll
    for (int i = 0; i < 16; i++) acc[i] = 0.f;
    int pr = tid >> 3;                   // PV row 0..31
    int pl = tid & 7;                    // PV d-lane
    for (int jt = it; jt >= 0; jt--) {
        int j0 = jt * 32;
        __syncthreads();                 // protect ks/vs/sw reuse (and Q tile on first iter)
#pragma unroll
        for (int p = 0; p < 4; p++) {
            int f = tid + 256 * p;
            int r = f >> 5, d4 = f & 31;
            size_t base = ((size_t)(b * T_ + j0 + r)) * 1024 + h * HS_ + d4 * 4;
            float4 kv = *(const float4*)&kmat[base];
            ks[r][d4 * 4 + 0] = kv.x; ks[r][d4 * 4 + 1] = kv.y;
            ks[r][d4 * 4 + 2] = kv.z; ks[r][d4 * 4 + 3] = kv.w;
            *(float4*)&vs[r][d4 * 4] = *(const float4*)&vmat[base];
        }
        __syncthreads();
        // scores: 32x32 dots over HS=128
#pragma unroll
        for (int pp = 0; pp < 4; pp++) {
            int pidx = tid + 256 * pp;
            int r = pidx >> 5, j = pidx & 31;
            float dot = 0.f;
#pragma unroll 8
            for (int d = 0; d < 128; d++) dot += qs[r][d] * ks[j][d];
            sw[r][j] = dot * 0.08838834764831845f;   // 1/sqrt(128)
        }
        __syncthreads();
        // backward stick-breaking scan, one thread per row
        if (tid < 32) {
            int ig = i0 + tid;
            float run = running;
            for (int j = 31; j >= 0; j--) {
                int jg = j0 + j;
                if (jg <= ig) {
                    float s = sw[tid][j];
                    float a = fabsf(s);
                    float t = log1pf(__expf(-a));
                    float lz = (s >= 0.f) ? -t : (s - t);   // log_sigmoid(s)
                    sw[tid][j] = __expf(lz + run);          // attention weight
                    run -= t + fmaxf(s, 0.f);               // += log(1 - sigmoid(s))
                } else {
                    sw[tid][j] = 0.f;
                }
            }
            running = run;
        }
        __syncthreads();
        // PV accumulate
        for (int j = 0; j < 32; j++) {
            float w = sw[pr][j];
#pragma unroll
            for (int dd = 0; dd < 16; dd++)
                acc[dd] += w * vs[j][pl + 8 * dd];
        }
    }
    // epilogue: fold gate in
    size_t pair = (size_t)(b * T_ + i0 + pr) * 2 + slot;
    float g = gates[pair];
    float* yp = y + pair * 1024 + h * HS_;
#pragma unroll
    for (int dd = 0; dd < 16; dd++)
        yp[pl + 8 * dd] = acc[dd] * g;
}

// ---------------- kernel 6: combine pairs + aux loss ----------------
__global__ __launch_bounds__(256) void combine_kernel(
    const float* __restrict__ tmp, float* __restrict__ out,
    const float* __restrict__ probs_sum, const float* __restrict__ frac_cnt,
    float* __restrict__ aux_out)
{
    int idx = blockIdx.x * 256 + threadIdx.x;   // float4 index over 1024*1024/4
    int token = idx >> 8;
    int c4 = idx & 255;
    const float4* t4 = (const float4*)tmp;
    float4 a = t4[(size_t)(token * 2) * 256 + c4];
    float4 b = t4[(size_t)(token * 2 + 1) * 256 + c4];
    float4 r;
    r.x = a.x + b.x; r.y = a.y + b.y; r.z = a.z + b.z; r.w = a.w + b.w;
    ((float4*)out)[idx] = r;
    if (idx == 0) {
        float s = 0.f;
        for (int e = 0; e < E_; e++)
            s += (probs_sum[e] * (1.f / 1024.f)) * (frac_cnt[e] * (1.f / 1024.f));
        aux_out[0] = (float)E_ * s;
    }
}

extern "C" void kernel_launch(void* const* d_in, const int* in_sizes, int n_in,
                              void* d_out, int out_size, void* d_ws, size_t ws_size,
                              hipStream_t stream)
{
    const float* x     = (const float*)d_in[0];
    const float* Wg    = (const float*)d_in[1];
    const float* W_in  = (const float*)d_in[2];
    const float* W_out = (const float*)d_in[3];
    const float* Wk    = (const float*)d_in[4];
    const float* bk    = (const float*)d_in[5];
    const float* Wv    = (const float*)d_in[6];
    const float* bv    = (const float*)d_in[7];

    char* ws = (char*)d_ws;
    float* probs_sum  = (float*)ws;            // 8 f
    float* frac_cnt   = probs_sum + 8;         // 8 f
    int*   bucket_cnt = (int*)(frac_cnt + 8);  // 8 i
    size_t off = 256;
    float* gates = (float*)(ws + off); off += (size_t)NPAIR * 4;          // 8 KB
    int* buckets = (int*)(ws + off);   off += (size_t)E_ * NPAIR * 4;     // 64 KB
    off = (off + 255) & ~(size_t)255;
    float* qbuf = (float*)(ws + off); off += (size_t)NPAIR * AH_ * 4;     // 8 MB
    float* kbuf = (float*)(ws + off); off += (size_t)NTOK * AH_ * 4;      // 4 MB
    float* vbuf = (float*)(ws + off); off += (size_t)NTOK * AH_ * 4;      // 4 MB
    float* ybuf = (float*)(ws + off); off += (size_t)NPAIR * AH_ * 4;     // 8 MB
    float* tmp  = qbuf;  // q is dead after attention; reuse for pair outputs

    hipMemsetAsync(ws, 0, 96, stream);  // zero probs_sum / frac_cnt / bucket_cnt

    gate_kernel<<<NTOK, 64, 0, stream>>>(x, Wg, gates, probs_sum, frac_cnt,
                                         bucket_cnt, buckets);
    kv_gemm<<<dim3(16, 32), 256, 0, stream>>>(x, Wk, bk, Wv, bv, kbuf, vbuf);
    routed_gemm<<<dim3(E_ * 32, 16), 256, 0, stream>>>(x, W_in, bucket_cnt, buckets,
                                                       1, qbuf);
    attn_kernel<<<dim3(32, 16), 256, 0, stream>>>(qbuf, kbuf, vbuf, gates, ybuf);
    routed_gemm<<<dim3(E_ * 32, 16), 256, 0, stream>>>(ybuf, W_out, bucket_cnt, buckets,
                                                       0, tmp);
    combine_kernel<<<(NTOK * C_ / 4) / 256, 256, 0, stream>>>(
        tmp, (float*)d_out, probs_sum, frac_cnt, (float*)d_out + (out_size - 1));
}

// Round 2
// 720.416 us; speedup vs baseline: 1.7649x; 1.7649x over previous
//
#include <hip/hip_runtime.h>
#include <cmath>

#define B_    2
#define T_    512
#define C_    1024
#define E_    8
#define NTOK  1024
#define NPAIR 2048
#define AH_   1024
#define NH_   8
#define HS_   128

typedef unsigned short u16;
typedef __attribute__((ext_vector_type(8))) short bf16x8;
typedef __attribute__((ext_vector_type(4))) float f32x4;

__device__ __forceinline__ u16 f2bf(float f) {
    union { float f; unsigned u; } v; v.f = f;
    unsigned r = v.u + 0x7fff + ((v.u >> 16) & 1);   // RNE
    return (u16)(r >> 16);
}

__device__ __forceinline__ void gload_lds16(const void* g, void* l) {
    __builtin_amdgcn_global_load_lds(
        (const __attribute__((address_space(1))) void*)g,
        (__attribute__((address_space(3))) void*)l, 16, 0, 0);
}

// ---------------- kernel 1: gates, top-2 routing, aux accumulators ----------------
__global__ __launch_bounds__(64) void gate_kernel(
    const float* __restrict__ x, const float* __restrict__ Wg,
    float* __restrict__ gates, float* __restrict__ probs_sum,
    float* __restrict__ frac_cnt, int* __restrict__ bucket_cnt,
    int* __restrict__ buckets)
{
    int token = blockIdx.x;
    int lane  = threadIdx.x;
    const float* xr = x + (size_t)token * C_;
    float acc[E_];
#pragma unroll
    for (int e = 0; e < E_; e++) acc[e] = 0.f;
    for (int c = lane; c < C_; c += 64) {
        float xv = xr[c];
        const float* wr = Wg + c * E_;
#pragma unroll
        for (int e = 0; e < E_; e++) acc[e] += xv * wr[e];
    }
#pragma unroll
    for (int e = 0; e < E_; e++) {
        float v = acc[e];
        v += __shfl_xor(v, 32); v += __shfl_xor(v, 16); v += __shfl_xor(v, 8);
        v += __shfl_xor(v, 4);  v += __shfl_xor(v, 2);  v += __shfl_xor(v, 1);
        acc[e] = v;
    }
    if (lane == 0) {
        int i0 = 0; float v0 = acc[0];
        for (int e = 1; e < E_; e++) if (acc[e] > v0) { v0 = acc[e]; i0 = e; }
        int i1 = -1; float v1 = -3.4e38f;
        for (int e = 0; e < E_; e++) if (e != i0 && acc[e] > v1) { v1 = acc[e]; i1 = e; }
        float e1  = __expf(v1 - v0);
        float inv = 1.f / (1.f + e1);
        gates[token * 2 + 0] = inv;
        gates[token * 2 + 1] = e1 * inv;
        float s = 0.f; float pe[E_];
        for (int e = 0; e < E_; e++) { pe[e] = __expf(acc[e] - v0); s += pe[e]; }
        float sinv = 1.f / s;
        for (int e = 0; e < E_; e++) atomicAdd(&probs_sum[e], pe[e] * sinv);
        atomicAdd(&frac_cnt[i0], 1.f);
        atomicAdd(&frac_cnt[i1], 1.f);
        int p0 = atomicAdd(&bucket_cnt[i0], 1);
        buckets[i0 * NPAIR + p0] = token * 2 + 0;
        int p1 = atomicAdd(&bucket_cnt[i1], 1);
        buckets[i1 * NPAIR + p1] = token * 2 + 1;
    }
}

// ---------------- convert x -> bf16, build concat bias ----------------
__global__ __launch_bounds__(256) void xcvt(
    const float* __restrict__ x, u16* __restrict__ xb,
    const float* __restrict__ bk, const float* __restrict__ bv,
    float* __restrict__ bkv)
{
    if (blockIdx.x == 1024) {
        for (int i = threadIdx.x; i < 2048; i += 256)
            bkv[i] = (i < 1024) ? bk[i] : bv[i - 1024];
        return;
    }
    int idx = blockIdx.x * 256 + threadIdx.x;     // float4 index over 1M/4
    float4 v = ((const float4*)x)[idx];
    ushort4 o;
    o.x = f2bf(v.x); o.y = f2bf(v.y); o.z = f2bf(v.z); o.w = f2bf(v.w);
    ((ushort4*)xb)[idx] = o;
}

// ---------------- transpose+convert one (or z-many) 1024x1024 fp32 -> bf16 [n][k] ----------------
__global__ __launch_bounds__(256) void transpose_cvt(
    const float* __restrict__ src, u16* __restrict__ dst)
{
    __shared__ float t[64][65];
    size_t mb = (size_t)blockIdx.z << 20;
    src += mb; dst += mb;
    int r0 = blockIdx.y * 64, c0 = blockIdx.x * 64;
    int tid = threadIdx.x;
#pragma unroll
    for (int p = 0; p < 4; p++) {
        int e4 = tid + 256 * p;              // 1024 float4s = 64x64
        int r = e4 >> 4, c4 = e4 & 15;
        float4 v = *(const float4*)&src[(size_t)(r0 + r) * 1024 + c0 + c4 * 4];
        t[r][c4 * 4 + 0] = v.x; t[r][c4 * 4 + 1] = v.y;
        t[r][c4 * 4 + 2] = v.z; t[r][c4 * 4 + 3] = v.w;
    }
    __syncthreads();
#pragma unroll
    for (int p = 0; p < 16; p++) {
        int e = tid + 256 * p;
        int r = e >> 6, c = e & 63;
        dst[(size_t)(c0 + r) * 1024 + r0 + c] = f2bf(t[c][r]);
    }
}

// ---------------- unified bf16 MFMA GEMM ----------------
// Out[row][n] = sum_k A[arow][k] * Wt[e][n][k]  (+bias[n])
// BM=128 BN=64 BK=32; block=256 (4 waves, each 32m x 64n)
// dense (buckets==null): mt=blockIdx.x, rows m0..; routed: e=bx>>4, mt=bx&15, rows gathered
__global__ __launch_bounds__(256) void gemm_bf16(
    const u16* __restrict__ A, const u16* __restrict__ Wt,
    const float* __restrict__ bias,
    const int* __restrict__ bucket_cnt, const int* __restrict__ buckets,
    int rowshift, float* __restrict__ Out, int out_stride, int Mdense)
{
    __shared__ __align__(16) u16 As[128 * 32];
    __shared__ __align__(16) u16 Bs[64 * 32];
    __shared__ int rowArr[128];
    int tid = threadIdx.x;
    int e, mt, cnt;
    int nt = blockIdx.y;
    if (buckets) { e = blockIdx.x >> 4; mt = blockIdx.x & 15; cnt = bucket_cnt[e]; }
    else         { e = 0;               mt = blockIdx.x;      cnt = Mdense; }
    int m0 = mt * 128;
    if (m0 >= cnt) return;
    int cl = min(cnt - m0, 128);
    if (tid < 128) {
        int idx = m0 + tid;
        rowArr[tid] = buckets ? buckets[e * NPAIR + (idx < cnt ? idx : cnt - 1)]
                              : idx;
    }
    __syncthreads();

    // staging lane constants: lane f covers LDS 16B chunk f; r=f>>2, phys chunk p=f&3
    // physical chunk p of row r holds logical k-chunk g=(p-(r>>1))&3  (2-way-max bank swizzle)
    int r0 = tid >> 2, p0 = tid & 3;
    int g0 = (p0 - ((r0 >> 1) & 3)) & 3;
    const u16* gA0p = A + (size_t)(rowArr[r0] >> rowshift) * 1024 + g0 * 8;
    const u16* gA1p = A + (size_t)(rowArr[r0 + 64] >> rowshift) * 1024 + g0 * 8;
    const u16* WtE  = Wt + ((size_t)e << 20) + (size_t)nt * 64 * 1024;
    const u16* gBp  = WtE + (size_t)r0 * 1024 + g0 * 8;

    int w    = tid >> 6;        // wave id
    int lane = tid & 63;
    int lm   = lane & 15;       // fragment row/col within 16
    int g    = lane >> 4;       // k-chunk for input fragments

    // LDS read offsets (u16 units), with matching swizzle
    int offA[2], offB[4];
#pragma unroll
    for (int i = 0; i < 2; i++) {
        int m = w * 32 + i * 16 + lm;
        offA[i] = m * 32 + (((g + ((m >> 1) & 3)) & 3) << 3);
    }
#pragma unroll
    for (int j = 0; j < 4; j++) {
        int n = j * 16 + lm;
        offB[j] = n * 32 + (((g + ((n >> 1) & 3)) & 3) << 3);
    }

    f32x4 acc[2][4];
#pragma unroll
    for (int i = 0; i < 2; i++)
#pragma unroll
        for (int j = 0; j < 4; j++) acc[i][j] = 0;

    u16* ldsA0 = As + w * 512;            // bytes: w*1024
    u16* ldsA1 = As + 2048 + w * 512;     // bytes: 4096 + w*1024
    u16* ldsB  = Bs + w * 512;

    for (int k0 = 0; k0 < 1024; k0 += 32) {
        __syncthreads();
        gload_lds16(gA0p + k0, ldsA0);
        gload_lds16(gA1p + k0, ldsA1);
        gload_lds16(gBp  + k0, ldsB);
        asm volatile("s_waitcnt vmcnt(0)" ::: "memory");
        __syncthreads();
        bf16x8 af[2], bfr[4];
#pragma unroll
        for (int i = 0; i < 2; i++) af[i] = *(const bf16x8*)&As[offA[i]];
#pragma unroll
        for (int j = 0; j < 4; j++) bfr[j] = *(const bf16x8*)&Bs[offB[j]];
#pragma unroll
        for (int i = 0; i < 2; i++)
#pragma unroll
            for (int j = 0; j < 4; j++)
                acc[i][j] = __builtin_amdgcn_mfma_f32_16x16x32_bf16(
                    af[i], bfr[j], acc[i][j], 0, 0, 0);
    }

    // epilogue: D layout col=lane&15, row=(lane>>4)*4+reg
    int rq = g;                  // (lane>>4)
#pragma unroll
    for (int i = 0; i < 2; i++) {
#pragma unroll
        for (int reg = 0; reg < 4; reg++) {
            int lrow = w * 32 + i * 16 + rq * 4 + reg;
            if (lrow < cl) {
                int orow = rowArr[lrow];
#pragma unroll
                for (int j = 0; j < 4; j++) {
                    int col = nt * 64 + j * 16 + lm;
                    float v = acc[i][j][reg];
                    if (bias) v += bias[col];
                    Out[(size_t)orow * out_stride + col] = v;
                }
            }
        }
    }
}

// ---------------- stick-breaking attention (fp32), kv fused buffer ----------------
// grid: (32 combos = b*16+slot*8+h, 16 i-tiles)  block: 256
__global__ __launch_bounds__(256) void attn_kernel(
    const float* __restrict__ q, const float* __restrict__ kv,
    const float* __restrict__ gates, u16* __restrict__ y)
{
    int combo = blockIdx.x;
    int it    = blockIdx.y;
    int b = combo >> 4, slot = (combo >> 3) & 1, h = combo & 7;
    int i0 = it * 32;
    __shared__ __align__(16) float qs[32][128];
    __shared__ float ks[32][129];
    __shared__ __align__(16) float vs[32][128];
    __shared__ float sw[32][33];
    int tid = threadIdx.x;
#pragma unroll
    for (int p = 0; p < 4; p++) {
        int f = tid + 256 * p;
        int r = f >> 5, d4 = f & 31;
        *(float4*)&qs[r][d4 * 4] =
            *(const float4*)&q[((size_t)((b * T_ + i0 + r) * 2 + slot)) * 1024 + h * HS_ + d4 * 4];
    }
    float running = 0.f;
    float acc[16];
#pragma unroll
    for (int i = 0; i < 16; i++) acc[i] = 0.f;
    int pr = tid >> 3;
    int pl = tid & 7;
    for (int jt = it; jt >= 0; jt--) {
        int j0 = jt * 32;
        __syncthreads();
#pragma unroll
        for (int p = 0; p < 4; p++) {
            int f = tid + 256 * p;
            int r = f >> 5, d4 = f & 31;
            size_t base = ((size_t)(b * T_ + j0 + r)) * 2048 + h * HS_ + d4 * 4;
            float4 kk = *(const float4*)&kv[base];
            ks[r][d4 * 4 + 0] = kk.x; ks[r][d4 * 4 + 1] = kk.y;
            ks[r][d4 * 4 + 2] = kk.z; ks[r][d4 * 4 + 3] = kk.w;
            *(float4*)&vs[r][d4 * 4] = *(const float4*)&kv[base + 1024];
        }
        __syncthreads();
#pragma unroll
        for (int pp = 0; pp < 4; pp++) {
            int pidx = tid + 256 * pp;
            int r = pidx >> 5, j = pidx & 31;
            float dot = 0.f;
#pragma unroll 8
            for (int d = 0; d < 128; d++) dot += qs[r][d] * ks[j][d];
            sw[r][j] = dot * 0.08838834764831845f;
        }
        __syncthreads();
        if (tid < 32) {
            int ig = i0 + tid;
            float run = running;
            for (int j = 31; j >= 0; j--) {
                int jg = j0 + j;
                if (jg <= ig) {
                    float s = sw[tid][j];
                    float a = fabsf(s);
                    float t = log1pf(__expf(-a));
                    float lz = (s >= 0.f) ? -t : (s - t);
                    sw[tid][j] = __expf(lz + run);
                    run -= t + fmaxf(s, 0.f);
                } else {
                    sw[tid][j] = 0.f;
                }
            }
            running = run;
        }
        __syncthreads();
        for (int j = 0; j < 32; j++) {
            float wgt = sw[pr][j];
#pragma unroll
            for (int dd = 0; dd < 16; dd++)
                acc[dd] += wgt * vs[j][pl + 8 * dd];
        }
    }
    size_t pair = (size_t)(b * T_ + i0 + pr) * 2 + slot;
    float gte = gates[pair];
    u16* yp = y + pair * 1024 + h * HS_;
#pragma unroll
    for (int dd = 0; dd < 16; dd++)
        yp[pl + 8 * dd] = f2bf(acc[dd] * gte);
}

// ---------------- combine pairs + aux loss ----------------
__global__ __launch_bounds__(256) void combine_kernel(
    const float* __restrict__ tmp, float* __restrict__ out,
    const float* __restrict__ probs_sum, const float* __restrict__ frac_cnt,
    float* __restrict__ aux_out)
{
    int idx = blockIdx.x * 256 + threadIdx.x;
    int token = idx >> 8;
    int c4 = idx & 255;
    const float4* t4 = (const float4*)tmp;
    float4 a = t4[(size_t)(token * 2) * 256 + c4];
    float4 b = t4[(size_t)(token * 2 + 1) * 256 + c4];
    float4 r;
    r.x = a.x + b.x; r.y = a.y + b.y; r.z = a.z + b.z; r.w = a.w + b.w;
    ((float4*)out)[idx] = r;
    if (idx == 0) {
        float s = 0.f;
        for (int e = 0; e < E_; e++)
            s += (probs_sum[e] * (1.f / 1024.f)) * (frac_cnt[e] * (1.f / 1024.f));
        aux_out[0] = (float)E_ * s;
    }
}

extern "C" void kernel_launch(void* const* d_in, const int* in_sizes, int n_in,
                              void* d_out, int out_size, void* d_ws, size_t ws_size,
                              hipStream_t stream)
{
    const float* x     = (const float*)d_in[0];
    const float* Wg    = (const float*)d_in[1];
    const float* W_in  = (const float*)d_in[2];
    const float* W_out = (const float*)d_in[3];
    const float* Wk    = (const float*)d_in[4];
    const float* bk    = (const float*)d_in[5];
    const float* Wv    = (const float*)d_in[6];
    const float* bv    = (const float*)d_in[7];

    char* ws = (char*)d_ws;
    float* probs_sum  = (float*)ws;
    float* frac_cnt   = probs_sum + 8;
    int*   bucket_cnt = (int*)(frac_cnt + 8);
    size_t off = 256;
    float* gates = (float*)(ws + off); off += (size_t)NPAIR * 4;              // 8 KB
    int* buckets = (int*)(ws + off);   off += (size_t)E_ * NPAIR * 4;         // 64 KB
    float* bkv   = (float*)(ws + off); off += 2048 * 4;                       // 8 KB
    off = (off + 255) & ~(size_t)255;
    u16* xb     = (u16*)(ws + off);   off += (size_t)NTOK * C_ * 2;           // 2 MB
    u16* Wkv_t  = (u16*)(ws + off);   off += (size_t)2048 * 1024 * 2;         // 4 MB
    u16* wt     = (u16*)(ws + off);   off += (size_t)E_ * 1024 * 1024 * 2;    // 16 MB (W_in_t then W_out_t)
    u16* yb     = (u16*)(ws + off);   off += (size_t)NPAIR * AH_ * 2;         // 4 MB
    float* qbuf = (float*)(ws + off); off += (size_t)NPAIR * AH_ * 4;         // 8 MB
    float* kvbuf= (float*)(ws + off); off += (size_t)NTOK * 2048 * 4;         // 8 MB
    float* tmp  = qbuf;   // q dead after attention

    hipMemsetAsync(ws, 0, 96, stream);

    gate_kernel<<<NTOK, 64, 0, stream>>>(x, Wg, gates, probs_sum, frac_cnt,
                                         bucket_cnt, buckets);
    xcvt<<<1025, 256, 0, stream>>>(x, xb, bk, bv, bkv);
    transpose_cvt<<<dim3(16, 16, 8), 256, 0, stream>>>(W_in, wt);
    transpose_cvt<<<dim3(16, 16, 1), 256, 0, stream>>>(Wk, Wkv_t);
    transpose_cvt<<<dim3(16, 16, 1), 256, 0, stream>>>(Wv, Wkv_t + (size_t)1024 * 1024);

    // K,V projection: dense, N=2048
    gemm_bf16<<<dim3(8, 32), 256, 0, stream>>>(xb, Wkv_t, bkv, nullptr, nullptr,
                                               0, kvbuf, 2048, NTOK);
    // q projection: routed, gather token = pair>>1
    gemm_bf16<<<dim3(E_ * 16, 16), 256, 0, stream>>>(xb, wt, nullptr, bucket_cnt,
                                                     buckets, 1, qbuf, 1024, 0);
    attn_kernel<<<dim3(32, 16), 256, 0, stream>>>(qbuf, kvbuf, gates, yb);

    // overwrite wt with W_out_t (stream-ordered after q gemm consumed W_in_t)
    transpose_cvt<<<dim3(16, 16, 8), 256, 0, stream>>>(W_out, wt);
    // output projection: routed, gather row = pair
    gemm_bf16<<<dim3(E_ * 16, 16), 256, 0, stream>>>(yb, wt, nullptr, bucket_cnt,
                                                     buckets, 0, tmp, 1024, 0);

    combine_kernel<<<(NTOK * C_ / 4) / 256, 256, 0, stream>>>(
        tmp, (float*)d_out, probs_sum, frac_cnt, (float*)d_out + (out_size - 1));
}

// Round 3
// 464.507 us; speedup vs baseline: 2.7372x; 1.5509x over previous
//
#include <hip/hip_runtime.h>
#include <cmath>

#define B_    2
#define T_    512
#define C_    1024
#define E_    8
#define NTOK  1024
#define NPAIR 2048
#define AH_   1024
#define NH_   8
#define HS_   128

typedef unsigned short u16;
typedef __attribute__((ext_vector_type(8))) short bf16x8;
typedef __attribute__((ext_vector_type(4))) float f32x4;

__device__ __forceinline__ u16 f2bf(float f) {
    union { float f; unsigned u; } v; v.f = f;
    unsigned r = v.u + 0x7fff + ((v.u >> 16) & 1);   // RNE
    return (u16)(r >> 16);
}

__device__ __forceinline__ void gload_lds16(const void* g, void* l) {
    __builtin_amdgcn_global_load_lds(
        (const __attribute__((address_space(1))) void*)g,
        (__attribute__((address_space(3))) void*)l, 16, 0, 0);
}

// ---------------- kernel 1: gates, top-2 routing, aux accumulators ----------------
__global__ __launch_bounds__(64) void gate_kernel(
    const float* __restrict__ x, const float* __restrict__ Wg,
    float* __restrict__ gates, float* __restrict__ probs_sum,
    float* __restrict__ frac_cnt, int* __restrict__ bucket_cnt,
    int* __restrict__ buckets)
{
    int token = blockIdx.x;
    int lane  = threadIdx.x;
    const float* xr = x + (size_t)token * C_;
    float acc[E_];
#pragma unroll
    for (int e = 0; e < E_; e++) acc[e] = 0.f;
    for (int c = lane; c < C_; c += 64) {
        float xv = xr[c];
        const float* wr = Wg + c * E_;
#pragma unroll
        for (int e = 0; e < E_; e++) acc[e] += xv * wr[e];
    }
#pragma unroll
    for (int e = 0; e < E_; e++) {
        float v = acc[e];
        v += __shfl_xor(v, 32); v += __shfl_xor(v, 16); v += __shfl_xor(v, 8);
        v += __shfl_xor(v, 4);  v += __shfl_xor(v, 2);  v += __shfl_xor(v, 1);
        acc[e] = v;
    }
    if (lane == 0) {
        int i0 = 0; float v0 = acc[0];
        for (int e = 1; e < E_; e++) if (acc[e] > v0) { v0 = acc[e]; i0 = e; }
        int i1 = -1; float v1 = -3.4e38f;
        for (int e = 0; e < E_; e++) if (e != i0 && acc[e] > v1) { v1 = acc[e]; i1 = e; }
        float e1  = __expf(v1 - v0);
        float inv = 1.f / (1.f + e1);
        gates[token * 2 + 0] = inv;
        gates[token * 2 + 1] = e1 * inv;
        float s = 0.f; float pe[E_];
        for (int e = 0; e < E_; e++) { pe[e] = __expf(acc[e] - v0); s += pe[e]; }
        float sinv = 1.f / s;
        for (int e = 0; e < E_; e++) atomicAdd(&probs_sum[e], pe[e] * sinv);
        atomicAdd(&frac_cnt[i0], 1.f);
        atomicAdd(&frac_cnt[i1], 1.f);
        int p0 = atomicAdd(&bucket_cnt[i0], 1);
        buckets[i0 * NPAIR + p0] = token * 2 + 0;
        int p1 = atomicAdd(&bucket_cnt[i1], 1);
        buckets[i1 * NPAIR + p1] = token * 2 + 1;
    }
}

// ---------------- convert x -> bf16, build concat bias ----------------
__global__ __launch_bounds__(256) void xcvt(
    const float* __restrict__ x, u16* __restrict__ xb,
    const float* __restrict__ bk, const float* __restrict__ bv,
    float* __restrict__ bkv)
{
    if (blockIdx.x == 1024) {
        for (int i = threadIdx.x; i < 2048; i += 256)
            bkv[i] = (i < 1024) ? bk[i] : bv[i - 1024];
        return;
    }
    int idx = blockIdx.x * 256 + threadIdx.x;
    float4 v = ((const float4*)x)[idx];
    ushort4 o;
    o.x = f2bf(v.x); o.y = f2bf(v.y); o.z = f2bf(v.z); o.w = f2bf(v.w);
    ((ushort4*)xb)[idx] = o;
}

// ---------------- transpose+convert 1024x1024 fp32 -> bf16 [n][k] ----------------
__global__ __launch_bounds__(256) void transpose_cvt(
    const float* __restrict__ src, u16* __restrict__ dst)
{
    __shared__ float t[64][65];
    size_t mb = (size_t)blockIdx.z << 20;
    src += mb; dst += mb;
    int r0 = blockIdx.y * 64, c0 = blockIdx.x * 64;
    int tid = threadIdx.x;
#pragma unroll
    for (int p = 0; p < 4; p++) {
        int e4 = tid + 256 * p;
        int r = e4 >> 4, c4 = e4 & 15;
        float4 v = *(const float4*)&src[(size_t)(r0 + r) * 1024 + c0 + c4 * 4];
        t[r][c4 * 4 + 0] = v.x; t[r][c4 * 4 + 1] = v.y;
        t[r][c4 * 4 + 2] = v.z; t[r][c4 * 4 + 3] = v.w;
    }
    __syncthreads();
#pragma unroll
    for (int p = 0; p < 16; p++) {
        int e = tid + 256 * p;
        int r = e >> 6, c = e & 63;
        dst[(size_t)(c0 + r) * 1024 + r0 + c] = f2bf(t[c][r]);
    }
}

// ---------------- unified bf16 MFMA GEMM ----------------
// mode 0: fp32 Out[orow][col]           (W_out -> tmp)
// mode 1: bf16 Qb[combo][i][d]          (routed q)
// mode 2: bf16 Kb / Vb [b,h][j][d] +bias (dense KV, N=2048)
__global__ __launch_bounds__(256) void gemm_bf16(
    const u16* __restrict__ A, const u16* __restrict__ Wt,
    const float* __restrict__ bias,
    const int* __restrict__ bucket_cnt, const int* __restrict__ buckets,
    int rowshift, float* __restrict__ OutF, u16* __restrict__ OutU,
    u16* __restrict__ OutV, int mode, int Mdense)
{
    __shared__ __align__(16) u16 As[128 * 32];
    __shared__ __align__(16) u16 Bs[64 * 32];
    __shared__ int rowArr[128];
    int tid = threadIdx.x;
    int e, mt, cnt;
    int nt = blockIdx.y;
    if (buckets) { e = blockIdx.x >> 4; mt = blockIdx.x & 15; cnt = bucket_cnt[e]; }
    else         { e = 0;               mt = blockIdx.x;      cnt = Mdense; }
    int m0 = mt * 128;
    if (m0 >= cnt) return;
    int cl = min(cnt - m0, 128);
    if (tid < 128) {
        int idx = m0 + tid;
        rowArr[tid] = buckets ? buckets[e * NPAIR + (idx < cnt ? idx : cnt - 1)]
                              : idx;
    }
    __syncthreads();

    int r0 = tid >> 2, p0 = tid & 3;
    int g0 = (p0 - ((r0 >> 1) & 3)) & 3;
    const u16* gA0p = A + (size_t)(rowArr[r0] >> rowshift) * 1024 + g0 * 8;
    const u16* gA1p = A + (size_t)(rowArr[r0 + 64] >> rowshift) * 1024 + g0 * 8;
    const u16* WtE  = Wt + ((size_t)e << 20) + (size_t)nt * 64 * 1024;
    const u16* gBp  = WtE + (size_t)r0 * 1024 + g0 * 8;

    int w    = tid >> 6;
    int lane = tid & 63;
    int lm   = lane & 15;
    int g    = lane >> 4;

    int offA[2], offB[4];
#pragma unroll
    for (int i = 0; i < 2; i++) {
        int m = w * 32 + i * 16 + lm;
        offA[i] = m * 32 + (((g + ((m >> 1) & 3)) & 3) << 3);
    }
#pragma unroll
    for (int j = 0; j < 4; j++) {
        int n = j * 16 + lm;
        offB[j] = n * 32 + (((g + ((n >> 1) & 3)) & 3) << 3);
    }

    f32x4 acc[2][4];
#pragma unroll
    for (int i = 0; i < 2; i++)
#pragma unroll
        for (int j = 0; j < 4; j++) acc[i][j] = 0;

    u16* ldsA0 = As + w * 512;
    u16* ldsA1 = As + 2048 + w * 512;
    u16* ldsB  = Bs + w * 512;

    for (int k0 = 0; k0 < 1024; k0 += 32) {
        __syncthreads();
        gload_lds16(gA0p + k0, ldsA0);
        gload_lds16(gA1p + k0, ldsA1);
        gload_lds16(gBp  + k0, ldsB);
        asm volatile("s_waitcnt vmcnt(0)" ::: "memory");
        __syncthreads();
        bf16x8 af[2], bfr[4];
#pragma unroll
        for (int i = 0; i < 2; i++) af[i] = *(const bf16x8*)&As[offA[i]];
#pragma unroll
        for (int j = 0; j < 4; j++) bfr[j] = *(const bf16x8*)&Bs[offB[j]];
#pragma unroll
        for (int i = 0; i < 2; i++)
#pragma unroll
            for (int j = 0; j < 4; j++)
                acc[i][j] = __builtin_amdgcn_mfma_f32_16x16x32_bf16(
                    af[i], bfr[j], acc[i][j], 0, 0, 0);
    }

    int rq = g;
#pragma unroll
    for (int i = 0; i < 2; i++) {
#pragma unroll
        for (int reg = 0; reg < 4; reg++) {
            int lrow = w * 32 + i * 16 + rq * 4 + reg;
            if (lrow < cl) {
                int orow = rowArr[lrow];
#pragma unroll
                for (int j = 0; j < 4; j++) {
                    int col = nt * 64 + j * 16 + lm;
                    float v = acc[i][j][reg];
                    if (bias) v += bias[col];
                    if (mode == 0) {
                        OutF[(size_t)orow * 1024 + col] = v;
                    } else if (mode == 1) {
                        int pb = orow >> 10, pi = (orow >> 1) & 511, ps = orow & 1;
                        int hh = col >> 7, dd = col & 127;
                        OutU[((((size_t)(pb * 16 + ps * 8 + hh)) * 512 + pi) << 7) + dd] = f2bf(v);
                    } else {
                        int tb = orow >> 9, tj = orow & 511;
                        int cc = col & 1023;
                        int hh = cc >> 7, dd = cc & 127;
                        u16* dst = (col < 1024) ? OutU : OutV;
                        dst[(((size_t)(tb * 8 + hh) * 512 + tj) << 7) + dd] = f2bf(v);
                    }
                }
            }
        }
    }
}

// ---------------- Vb [bh][j][d] -> Vtb [bh][d][j] (bf16 transpose) ----------------
__global__ __launch_bounds__(256) void vtrans(
    const u16* __restrict__ Vb, u16* __restrict__ Vtb)
{
    __shared__ u16 t[64][72];
    int bh = blockIdx.x;
    int d0 = blockIdx.y * 64;
    int j0 = blockIdx.z * 64;
    int tid = threadIdx.x;
#pragma unroll
    for (int p = 0; p < 2; p++) {
        int c = tid + 256 * p;
        int jr = c >> 3, c8 = c & 7;
        *(bf16x8*)&t[jr][c8 * 8] =
            *(const bf16x8*)&Vb[((size_t)bh * 512 + j0 + jr) * 128 + d0 + c8 * 8];
    }
    __syncthreads();
#pragma unroll
    for (int p = 0; p < 2; p++) {
        int c = tid + 256 * p;
        int dr = c >> 3, j8 = c & 7;
        bf16x8 o;
#pragma unroll
        for (int k = 0; k < 8; k++) o[k] = (short)t[j8 * 8 + k][dr];
        *(bf16x8*)&Vtb[((size_t)bh * 128 + d0 + dr) * 512 + j0 + j8 * 8] = o;
    }
}

// ---------------- stick-breaking flash attention, MFMA ----------------
// grid (32 combos, 8 balanced tile-pairs), block 256 (4 waves)
__global__ __launch_bounds__(256) void attn_kernel(
    const u16* __restrict__ Qb, const u16* __restrict__ Kb,
    const u16* __restrict__ Vtb, const float* __restrict__ gates,
    u16* __restrict__ yb)
{
    __shared__ __align__(16) u16 Qs[32 * 136];
    __shared__ __align__(16) u16 Ks[32 * 136];
    __shared__ __align__(16) u16 Vts[128 * 40];
    __shared__ __align__(16) float sw[32 * 36];
    __shared__ __align__(16) u16 wt[32 * 40];

    int combo = blockIdx.x;
    int b = combo >> 4, slot = (combo >> 3) & 1, h = combo & 7;
    int bh = b * 8 + h;
    const u16* Qbase = Qb  + ((size_t)combo << 16);
    const u16* Kbase = Kb  + ((size_t)bh << 16);
    const u16* Vbase = Vtb + ((size_t)bh << 16);

    int tid = threadIdx.x;
    int w = tid >> 6, lane = tid & 63, lm = lane & 15, g = lane >> 4;
    int mh = w >> 1, nh = w & 1, dsel = w & 1;
    int srow = tid >> 3, st = tid & 7;
    int rowlane = lane & 56;
    const float SCALE = 0.08838834764831845f;

    for (int seg = 0; seg < 2; seg++) {
        int it = seg ? (15 - blockIdx.y) : blockIdx.y;
        int i0 = it * 32;
        __syncthreads();
#pragma unroll
        for (int p = 0; p < 2; p++) {
            int c = tid + 256 * p;
            int r = c >> 4, c8 = c & 15;
            *(bf16x8*)&Qs[r * 136 + c8 * 8] =
                *(const bf16x8*)&Qbase[(size_t)(i0 + r) * 128 + c8 * 8];
        }
        f32x4 pacc[4];
#pragma unroll
        for (int q = 0; q < 4; q++) pacc[q] = 0;
        float running = 0.f;

        for (int jt = it; jt >= 0; jt--) {
            int j0 = jt * 32;
            __syncthreads();
#pragma unroll
            for (int p = 0; p < 2; p++) {
                int c = tid + 256 * p;
                int r = c >> 4, c8 = c & 15;
                *(bf16x8*)&Ks[r * 136 + c8 * 8] =
                    *(const bf16x8*)&Kbase[(size_t)(j0 + r) * 128 + c8 * 8];
            }
#pragma unroll
            for (int p = 0; p < 2; p++) {
                int c = tid + 256 * p;
                int d = c >> 2, j8 = c & 3;
                *(bf16x8*)&Vts[d * 40 + j8 * 8] =
                    *(const bf16x8*)&Vbase[(size_t)d * 512 + j0 + j8 * 8];
            }
            __syncthreads();
            // QK^T: each wave one 16x16 quadrant
            f32x4 sacc = 0;
#pragma unroll
            for (int ks = 0; ks < 4; ks++) {
                bf16x8 aq = *(const bf16x8*)&Qs[(mh * 16 + lm) * 136 + ks * 32 + g * 8];
                bf16x8 bk = *(const bf16x8*)&Ks[(nh * 16 + lm) * 136 + ks * 32 + g * 8];
                sacc = __builtin_amdgcn_mfma_f32_16x16x32_bf16(aq, bk, sacc, 0, 0, 0);
            }
#pragma unroll
            for (int reg = 0; reg < 4; reg++)
                sw[(mh * 16 + g * 4 + reg) * 36 + nh * 16 + lm] = sacc[reg] * SCALE;
            __syncthreads();
            // stick-breaking scan: 8 lanes per row
            {
                float4 sv = *(const float4*)&sw[srow * 36 + st * 4];
                float sarr[4] = {sv.x, sv.y, sv.z, sv.w};
                int ig = i0 + srow;
                float lsig[4], lb[4];
#pragma unroll
                for (int c2 = 0; c2 < 4; c2++) {
                    int jg = j0 + st * 4 + c2;
                    float sc = sarr[c2];
                    float a  = fabsf(sc);
                    float tl = log1pf(__expf(-a));
                    lsig[c2] = (sc >= 0.f) ? -tl : sc - tl;
                    lb[c2]   = (jg <= ig) ? -(tl + fmaxf(sc, 0.f)) : 0.f;
                }
                float suf[4];
                suf[3] = 0.f;
                suf[2] = lb[3];
                suf[1] = lb[2] + lb[3];
                suf[0] = lb[1] + suf[1];
                float total = lb[0] + suf[0];
                float incl = total;
                float y1 = __shfl_down(incl, 1, 64); if (st < 7) incl += y1;
                float y2 = __shfl_down(incl, 2, 64); if (st < 6) incl += y2;
                float y4 = __shfl_down(incl, 4, 64); if (st < 4) incl += y4;
                float basev = (incl - total) + running;
                ushort4 wo;
                float wv;
                int jgc = j0 + st * 4;
                wv = (jgc + 0 <= ig) ? __expf(lsig[0] + suf[0] + basev) : 0.f; wo.x = f2bf(wv);
                wv = (jgc + 1 <= ig) ? __expf(lsig[1] + suf[1] + basev) : 0.f; wo.y = f2bf(wv);
                wv = (jgc + 2 <= ig) ? __expf(lsig[2] + suf[2] + basev) : 0.f; wo.z = f2bf(wv);
                wv = (jgc + 3 <= ig) ? __expf(lsig[3] + suf[3] + basev) : 0.f; wo.w = f2bf(wv);
                running += __shfl(incl, rowlane, 64);
                *(ushort4*)&wt[srow * 40 + st * 4] = wo;
            }
            __syncthreads();
            // PV: weights (A) x V^T (B)
            bf16x8 aw = *(const bf16x8*)&wt[(mh * 16 + lm) * 40 + g * 8];
#pragma unroll
            for (int q = 0; q < 4; q++) {
                int dt = q * 2 + dsel;
                bf16x8 bv8 = *(const bf16x8*)&Vts[(dt * 16 + lm) * 40 + g * 8];
                pacc[q] = __builtin_amdgcn_mfma_f32_16x16x32_bf16(aw, bv8, pacc[q], 0, 0, 0);
            }
        }
        // epilogue: gate * y -> bf16
#pragma unroll
        for (int reg = 0; reg < 4; reg++) {
            int i = i0 + mh * 16 + g * 4 + reg;
            size_t pair = ((size_t)(b * 512 + i)) * 2 + slot;
            float gt = gates[pair];
#pragma unroll
            for (int q = 0; q < 4; q++) {
                int d = (q * 2 + dsel) * 16 + lm;
                yb[pair * 1024 + h * 128 + d] = f2bf(pacc[q][reg] * gt);
            }
        }
    }
}

// ---------------- combine pairs + aux loss ----------------
__global__ __launch_bounds__(256) void combine_kernel(
    const float* __restrict__ tmp, float* __restrict__ out,
    const float* __restrict__ probs_sum, const float* __restrict__ frac_cnt,
    float* __restrict__ aux_out)
{
    int idx = blockIdx.x * 256 + threadIdx.x;
    int token = idx >> 8;
    int c4 = idx & 255;
    const float4* t4 = (const float4*)tmp;
    float4 a = t4[(size_t)(token * 2) * 256 + c4];
    float4 b = t4[(size_t)(token * 2 + 1) * 256 + c4];
    float4 r;
    r.x = a.x + b.x; r.y = a.y + b.y; r.z = a.z + b.z; r.w = a.w + b.w;
    ((float4*)out)[idx] = r;
    if (idx == 0) {
        float s = 0.f;
        for (int e = 0; e < E_; e++)
            s += (probs_sum[e] * (1.f / 1024.f)) * (frac_cnt[e] * (1.f / 1024.f));
        aux_out[0] = (float)E_ * s;
    }
}

extern "C" void kernel_launch(void* const* d_in, const int* in_sizes, int n_in,
                              void* d_out, int out_size, void* d_ws, size_t ws_size,
                              hipStream_t stream)
{
    const float* x     = (const float*)d_in[0];
    const float* Wg    = (const float*)d_in[1];
    const float* W_in  = (const float*)d_in[2];
    const float* W_out = (const float*)d_in[3];
    const float* Wk    = (const float*)d_in[4];
    const float* bk    = (const float*)d_in[5];
    const float* Wv    = (const float*)d_in[6];
    const float* bv    = (const float*)d_in[7];

    char* ws = (char*)d_ws;
    float* probs_sum  = (float*)ws;
    float* frac_cnt   = probs_sum + 8;
    int*   bucket_cnt = (int*)(frac_cnt + 8);
    size_t off = 256;
    float* gates = (float*)(ws + off); off += (size_t)NPAIR * 4;
    int* buckets = (int*)(ws + off);   off += (size_t)E_ * NPAIR * 4;
    float* bkv   = (float*)(ws + off); off += 2048 * 4;
    off = (off + 255) & ~(size_t)255;
    u16* xb    = (u16*)(ws + off); off += (size_t)NTOK * C_ * 2;          // 2 MB
    u16* Wkv_t = (u16*)(ws + off); off += (size_t)2048 * 1024 * 2;        // 4 MB
    u16* wt    = (u16*)(ws + off); off += (size_t)E_ * 1024 * 1024 * 2;   // 16 MB
    u16* yb    = (u16*)(ws + off); off += (size_t)NPAIR * AH_ * 2;        // 4 MB
    u16* Qbuf  = (u16*)(ws + off); off += (size_t)32 * 512 * 128 * 2;     // 4 MB
    u16* Kbuf  = (u16*)(ws + off); off += (size_t)16 * 512 * 128 * 2;     // 2 MB
    u16* Vbuf  = (u16*)(ws + off); off += (size_t)16 * 512 * 128 * 2;     // 2 MB
    u16* Vtbuf = (u16*)(ws + off); off += (size_t)16 * 128 * 512 * 2;     // 2 MB
    float* tmp = (float*)(ws + off); off += (size_t)NPAIR * AH_ * 4;      // 8 MB

    hipMemsetAsync(ws, 0, 96, stream);

    gate_kernel<<<NTOK, 64, 0, stream>>>(x, Wg, gates, probs_sum, frac_cnt,
                                         bucket_cnt, buckets);
    xcvt<<<1025, 256, 0, stream>>>(x, xb, bk, bv, bkv);
    transpose_cvt<<<dim3(16, 16, 8), 256, 0, stream>>>(W_in, wt);
    transpose_cvt<<<dim3(16, 16, 1), 256, 0, stream>>>(Wk, Wkv_t);
    transpose_cvt<<<dim3(16, 16, 1), 256, 0, stream>>>(Wv, Wkv_t + (size_t)1024 * 1024);

    // K,V projection: dense, N=2048, bf16 out in attention layout
    gemm_bf16<<<dim3(8, 32), 256, 0, stream>>>(xb, Wkv_t, bkv, nullptr, nullptr,
                                               0, nullptr, Kbuf, Vbuf, 2, NTOK);
    // q projection: routed, bf16 out in [combo][i][d]
    gemm_bf16<<<dim3(E_ * 16, 16), 256, 0, stream>>>(xb, wt, nullptr, bucket_cnt,
                                                     buckets, 1, nullptr, Qbuf,
                                                     nullptr, 1, 0);
    vtrans<<<dim3(16, 2, 8), 256, 0, stream>>>(Vbuf, Vtbuf);

    attn_kernel<<<dim3(32, 8), 256, 0, stream>>>(Qbuf, Kbuf, Vtbuf, gates, yb);

    transpose_cvt<<<dim3(16, 16, 8), 256, 0, stream>>>(W_out, wt);
    gemm_bf16<<<dim3(E_ * 16, 16), 256, 0, stream>>>(yb, wt, nullptr, bucket_cnt,
                                                     buckets, 0, tmp, nullptr,
                                                     nullptr, 0, 0);

    combine_kernel<<<(NTOK * C_ / 4) / 256, 256, 0, stream>>>(
        tmp, (float*)d_out, probs_sum, frac_cnt, (float*)d_out + (out_size - 1));
}

// Round 4
// 333.188 us; speedup vs baseline: 3.8161x; 1.3941x over previous
//
#include <hip/hip_runtime.h>
#include <cmath>

#define B_    2
#define T_    512
#define C_    1024
#define E_    8
#define NTOK  1024
#define NPAIR 2048
#define AH_   1024
#define NH_   8
#define HS_   128

typedef unsigned short u16;
typedef __attribute__((ext_vector_type(8))) short bf16x8;
typedef __attribute__((ext_vector_type(4))) float f32x4;

__device__ __forceinline__ u16 f2bf(float f) {
    union { float f; unsigned u; } v; v.f = f;
    unsigned r = v.u + 0x7fff + ((v.u >> 16) & 1);   // RNE
    return (u16)(r >> 16);
}

__device__ __forceinline__ void gload_lds16(const void* g, void* l) {
    __builtin_amdgcn_global_load_lds(
        (const __attribute__((address_space(1))) void*)g,
        (__attribute__((address_space(3))) void*)l, 16, 0, 0);
}

// ---------------- kernel 1: gate logits, top-2, x->bf16 (NO global atomics) ----------------
__global__ __launch_bounds__(64) void gate_kernel(
    const float* __restrict__ x, const float* __restrict__ Wg,
    u16* __restrict__ xb, float* __restrict__ gates,
    float* __restrict__ probs, int* __restrict__ eass)
{
    int token = blockIdx.x;
    int lane  = threadIdx.x;
    const float* xr = x + (size_t)token * C_;
    u16* xbr = xb + (size_t)token * C_;
    float acc[E_];
#pragma unroll
    for (int e = 0; e < E_; e++) acc[e] = 0.f;
    for (int c = lane; c < C_; c += 64) {
        float xv = xr[c];
        xbr[c] = f2bf(xv);
        const float* wr = Wg + c * E_;
#pragma unroll
        for (int e = 0; e < E_; e++) acc[e] += xv * wr[e];
    }
#pragma unroll
    for (int e = 0; e < E_; e++) {
        float v = acc[e];
        v += __shfl_xor(v, 32); v += __shfl_xor(v, 16); v += __shfl_xor(v, 8);
        v += __shfl_xor(v, 4);  v += __shfl_xor(v, 2);  v += __shfl_xor(v, 1);
        acc[e] = v;
    }
    if (lane == 0) {
        int i0 = 0; float v0 = acc[0];
        for (int e = 1; e < E_; e++) if (acc[e] > v0) { v0 = acc[e]; i0 = e; }
        int i1 = -1; float v1 = -3.4e38f;
        for (int e = 0; e < E_; e++) if (e != i0 && acc[e] > v1) { v1 = acc[e]; i1 = e; }
        float e1  = __expf(v1 - v0);
        float inv = 1.f / (1.f + e1);
        gates[token * 2 + 0] = inv;
        gates[token * 2 + 1] = e1 * inv;
        float s = 0.f; float pe[E_];
        for (int e = 0; e < E_; e++) { pe[e] = __expf(acc[e] - v0); s += pe[e]; }
        float sinv = 1.f / s;
        for (int e = 0; e < E_; e++) probs[token * E_ + e] = pe[e] * sinv;
        eass[token * 2 + 0] = i0;
        eass[token * 2 + 1] = i1;
    }
}

// ---------------- kernel 1b: aux-loss reduce + bucket build (single block) ----------------
__global__ __launch_bounds__(256) void route_kernel(
    const float* __restrict__ probs, const int* __restrict__ eass,
    const float* __restrict__ bk, const float* __restrict__ bv,
    int* __restrict__ bucket_cnt, int* __restrict__ buckets,
    float* __restrict__ bkv, float* __restrict__ aux_out)
{
    __shared__ float red[256][17];
    __shared__ int lcnt[E_];
    int tid = threadIdx.x;
    for (int i = tid; i < 1024; i += 256) {
        bkv[i] = bk[i];
        bkv[i + 1024] = bv[i];
    }
    float ps[E_], fc[E_];
#pragma unroll
    for (int e = 0; e < E_; e++) { ps[e] = 0.f; fc[e] = 0.f; }
    for (int k = 0; k < 4; k++) {
        int row = tid + k * 256;
#pragma unroll
        for (int e = 0; e < E_; e++) ps[e] += probs[row * E_ + e];
    }
    for (int k = 0; k < 8; k++) {
        int i = tid + k * 256;
        int ea = eass[i];
#pragma unroll
        for (int e = 0; e < E_; e++) fc[e] += (ea == e) ? 1.f : 0.f;
    }
#pragma unroll
    for (int e = 0; e < E_; e++) { red[tid][e] = ps[e]; red[tid][8 + e] = fc[e]; }
    if (tid < E_) lcnt[tid] = 0;
    __syncthreads();
    for (int s = 128; s > 0; s >>= 1) {
        if (tid < s)
#pragma unroll
            for (int j = 0; j < 16; j++) red[tid][j] += red[tid + s][j];
        __syncthreads();
    }
    if (tid == 0) {
        float s = 0.f;
        for (int e = 0; e < E_; e++)
            s += (red[0][e] * (1.f / 1024.f)) * (red[0][8 + e] * (1.f / 1024.f));
        aux_out[0] = (float)E_ * s;
    }
    for (int k = 0; k < 8; k++) {
        int i = tid + k * 256;
        int ea = eass[i];
        int pos = atomicAdd(&lcnt[ea], 1);
        buckets[ea * NPAIR + pos] = i;
    }
    __syncthreads();
    if (tid < E_) bucket_cnt[tid] = lcnt[tid];
}

// ---------------- transpose+convert 1024x1024 fp32 -> bf16 [n][k] ----------------
__global__ __launch_bounds__(256) void transpose_cvt(
    const float* __restrict__ src, u16* __restrict__ dst)
{
    __shared__ float t[64][65];
    size_t mb = (size_t)blockIdx.z << 20;
    src += mb; dst += mb;
    int r0 = blockIdx.y * 64, c0 = blockIdx.x * 64;
    int tid = threadIdx.x;
#pragma unroll
    for (int p = 0; p < 4; p++) {
        int e4 = tid + 256 * p;
        int r = e4 >> 4, c4 = e4 & 15;
        float4 v = *(const float4*)&src[(size_t)(r0 + r) * 1024 + c0 + c4 * 4];
        t[r][c4 * 4 + 0] = v.x; t[r][c4 * 4 + 1] = v.y;
        t[r][c4 * 4 + 2] = v.z; t[r][c4 * 4 + 3] = v.w;
    }
    __syncthreads();
#pragma unroll
    for (int p = 0; p < 16; p++) {
        int e = tid + 256 * p;
        int r = e >> 6, c = e & 63;
        dst[(size_t)(c0 + r) * 1024 + r0 + c] = f2bf(t[c][r]);
    }
}

// ---------------- unified bf16 MFMA GEMM ----------------
// mode 0: fp32 Out[orow][col]           (W_out -> tmp)
// mode 1: bf16 Qb[combo][i][d]          (routed q)
// mode 2: bf16 Kb / Vb [b,h][j][d] +bias (dense KV, N=2048)
__global__ __launch_bounds__(256) void gemm_bf16(
    const u16* __restrict__ A, const u16* __restrict__ Wt,
    const float* __restrict__ bias,
    const int* __restrict__ bucket_cnt, const int* __restrict__ buckets,
    int rowshift, float* __restrict__ OutF, u16* __restrict__ OutU,
    u16* __restrict__ OutV, int mode, int Mdense)
{
    __shared__ __align__(16) u16 As[128 * 32];
    __shared__ __align__(16) u16 Bs[64 * 32];
    __shared__ int rowArr[128];
    int tid = threadIdx.x;
    int e, mt, cnt;
    int nt = blockIdx.y;
    if (buckets) { e = blockIdx.x >> 4; mt = blockIdx.x & 15; cnt = bucket_cnt[e]; }
    else         { e = 0;               mt = blockIdx.x;      cnt = Mdense; }
    int m0 = mt * 128;
    if (m0 >= cnt) return;
    int cl = min(cnt - m0, 128);
    if (tid < 128) {
        int idx = m0 + tid;
        rowArr[tid] = buckets ? buckets[e * NPAIR + (idx < cnt ? idx : cnt - 1)]
                              : idx;
    }
    __syncthreads();

    int r0 = tid >> 2, p0 = tid & 3;
    int g0 = (p0 - ((r0 >> 1) & 3)) & 3;
    const u16* gA0p = A + (size_t)(rowArr[r0] >> rowshift) * 1024 + g0 * 8;
    const u16* gA1p = A + (size_t)(rowArr[r0 + 64] >> rowshift) * 1024 + g0 * 8;
    const u16* WtE  = Wt + ((size_t)e << 20) + (size_t)nt * 64 * 1024;
    const u16* gBp  = WtE + (size_t)r0 * 1024 + g0 * 8;

    int w    = tid >> 6;
    int lane = tid & 63;
    int lm   = lane & 15;
    int g    = lane >> 4;

    int offA[2], offB[4];
#pragma unroll
    for (int i = 0; i < 2; i++) {
        int m = w * 32 + i * 16 + lm;
        offA[i] = m * 32 + (((g + ((m >> 1) & 3)) & 3) << 3);
    }
#pragma unroll
    for (int j = 0; j < 4; j++) {
        int n = j * 16 + lm;
        offB[j] = n * 32 + (((g + ((n >> 1) & 3)) & 3) << 3);
    }

    f32x4 acc[2][4];
#pragma unroll
    for (int i = 0; i < 2; i++)
#pragma unroll
        for (int j = 0; j < 4; j++) acc[i][j] = 0;

    u16* ldsA0 = As + w * 512;
    u16* ldsA1 = As + 2048 + w * 512;
    u16* ldsB  = Bs + w * 512;

    for (int k0 = 0; k0 < 1024; k0 += 32) {
        __syncthreads();
        gload_lds16(gA0p + k0, ldsA0);
        gload_lds16(gA1p + k0, ldsA1);
        gload_lds16(gBp  + k0, ldsB);
        asm volatile("s_waitcnt vmcnt(0)" ::: "memory");
        __syncthreads();
        bf16x8 af[2], bfr[4];
#pragma unroll
        for (int i = 0; i < 2; i++) af[i] = *(const bf16x8*)&As[offA[i]];
#pragma unroll
        for (int j = 0; j < 4; j++) bfr[j] = *(const bf16x8*)&Bs[offB[j]];
#pragma unroll
        for (int i = 0; i < 2; i++)
#pragma unroll
            for (int j = 0; j < 4; j++)
                acc[i][j] = __builtin_amdgcn_mfma_f32_16x16x32_bf16(
                    af[i], bfr[j], acc[i][j], 0, 0, 0);
    }

    int rq = g;
#pragma unroll
    for (int i = 0; i < 2; i++) {
#pragma unroll
        for (int reg = 0; reg < 4; reg++) {
            int lrow = w * 32 + i * 16 + rq * 4 + reg;
            if (lrow < cl) {
                int orow = rowArr[lrow];
#pragma unroll
                for (int j = 0; j < 4; j++) {
                    int col = nt * 64 + j * 16 + lm;
                    float v = acc[i][j][reg];
                    if (bias) v += bias[col];
                    if (mode == 0) {
                        OutF[(size_t)orow * 1024 + col] = v;
                    } else if (mode == 1) {
                        int pb = orow >> 10, pi = (orow >> 1) & 511, ps = orow & 1;
                        int hh = col >> 7, dd = col & 127;
                        OutU[((((size_t)(pb * 16 + ps * 8 + hh)) * 512 + pi) << 7) + dd] = f2bf(v);
                    } else {
                        int tb = orow >> 9, tj = orow & 511;
                        int cc = col & 1023;
                        int hh = cc >> 7, dd = cc & 127;
                        u16* dst = (col < 1024) ? OutU : OutV;
                        dst[(((size_t)(tb * 8 + hh) * 512 + tj) << 7) + dd] = f2bf(v);
                    }
                }
            }
        }
    }
}

// ---------------- Vb [bh][j][d] -> Vtb [bh][d][j] (bf16 transpose) ----------------
__global__ __launch_bounds__(256) void vtrans(
    const u16* __restrict__ Vb, u16* __restrict__ Vtb)
{
    __shared__ u16 t[64][72];
    int bh = blockIdx.x;
    int d0 = blockIdx.y * 64;
    int j0 = blockIdx.z * 64;
    int tid = threadIdx.x;
#pragma unroll
    for (int p = 0; p < 2; p++) {
        int c = tid + 256 * p;
        int jr = c >> 3, c8 = c & 7;
        *(bf16x8*)&t[jr][c8 * 8] =
            *(const bf16x8*)&Vb[((size_t)bh * 512 + j0 + jr) * 128 + d0 + c8 * 8];
    }
    __syncthreads();
#pragma unroll
    for (int p = 0; p < 2; p++) {
        int c = tid + 256 * p;
        int dr = c >> 3, j8 = c & 7;
        bf16x8 o;
#pragma unroll
        for (int k = 0; k < 8; k++) o[k] = (short)t[j8 * 8 + k][dr];
        *(bf16x8*)&Vtb[((size_t)bh * 128 + d0 + dr) * 512 + j0 + j8 * 8] = o;
    }
}

// ---------------- stick-breaking flash attention, MFMA ----------------
__global__ __launch_bounds__(256) void attn_kernel(
    const u16* __restrict__ Qb, const u16* __restrict__ Kb,
    const u16* __restrict__ Vtb, const float* __restrict__ gates,
    u16* __restrict__ yb)
{
    __shared__ __align__(16) u16 Qs[32 * 136];
    __shared__ __align__(16) u16 Ks[32 * 136];
    __shared__ __align__(16) u16 Vts[128 * 40];
    __shared__ __align__(16) float sw[32 * 36];
    __shared__ __align__(16) u16 wt[32 * 40];

    int combo = blockIdx.x;
    int b = combo >> 4, slot = (combo >> 3) & 1, h = combo & 7;
    int bh = b * 8 + h;
    const u16* Qbase = Qb  + ((size_t)combo << 16);
    const u16* Kbase = Kb  + ((size_t)bh << 16);
    const u16* Vbase = Vtb + ((size_t)bh << 16);

    int tid = threadIdx.x;
    int w = tid >> 6, lane = tid & 63, lm = lane & 15, g = lane >> 4;
    int mh = w >> 1, nh = w & 1, dsel = w & 1;
    int srow = tid >> 3, st = tid & 7;
    int rowlane = lane & 56;
    const float SCALE = 0.08838834764831845f;

    for (int seg = 0; seg < 2; seg++) {
        int it = seg ? (15 - blockIdx.y) : blockIdx.y;
        int i0 = it * 32;
        __syncthreads();
#pragma unroll
        for (int p = 0; p < 2; p++) {
            int c = tid + 256 * p;
            int r = c >> 4, c8 = c & 15;
            *(bf16x8*)&Qs[r * 136 + c8 * 8] =
                *(const bf16x8*)&Qbase[(size_t)(i0 + r) * 128 + c8 * 8];
        }
        f32x4 pacc[4];
#pragma unroll
        for (int q = 0; q < 4; q++) pacc[q] = 0;
        float running = 0.f;

        for (int jt = it; jt >= 0; jt--) {
            int j0 = jt * 32;
            __syncthreads();
#pragma unroll
            for (int p = 0; p < 2; p++) {
                int c = tid + 256 * p;
                int r = c >> 4, c8 = c & 15;
                *(bf16x8*)&Ks[r * 136 + c8 * 8] =
                    *(const bf16x8*)&Kbase[(size_t)(j0 + r) * 128 + c8 * 8];
            }
#pragma unroll
            for (int p = 0; p < 2; p++) {
                int c = tid + 256 * p;
                int d = c >> 2, j8 = c & 3;
                *(bf16x8*)&Vts[d * 40 + j8 * 8] =
                    *(const bf16x8*)&Vbase[(size_t)d * 512 + j0 + j8 * 8];
            }
            __syncthreads();
            f32x4 sacc = 0;
#pragma unroll
            for (int ks = 0; ks < 4; ks++) {
                bf16x8 aq = *(const bf16x8*)&Qs[(mh * 16 + lm) * 136 + ks * 32 + g * 8];
                bf16x8 bk = *(const bf16x8*)&Ks[(nh * 16 + lm) * 136 + ks * 32 + g * 8];
                sacc = __builtin_amdgcn_mfma_f32_16x16x32_bf16(aq, bk, sacc, 0, 0, 0);
            }
#pragma unroll
            for (int reg = 0; reg < 4; reg++)
                sw[(mh * 16 + g * 4 + reg) * 36 + nh * 16 + lm] = sacc[reg] * SCALE;
            __syncthreads();
            {
                float4 sv = *(const float4*)&sw[srow * 36 + st * 4];
                float sarr[4] = {sv.x, sv.y, sv.z, sv.w};
                int ig = i0 + srow;
                float lsig[4], lb[4];
#pragma unroll
                for (int c2 = 0; c2 < 4; c2++) {
                    int jg = j0 + st * 4 + c2;
                    float sc = sarr[c2];
                    float a  = fabsf(sc);
                    float tl = log1pf(__expf(-a));
                    lsig[c2] = (sc >= 0.f) ? -tl : sc - tl;
                    lb[c2]   = (jg <= ig) ? -(tl + fmaxf(sc, 0.f)) : 0.f;
                }
                float suf[4];
                suf[3] = 0.f;
                suf[2] = lb[3];
                suf[1] = lb[2] + lb[3];
                suf[0] = lb[1] + suf[1];
                float total = lb[0] + suf[0];
                float incl = total;
                float y1 = __shfl_down(incl, 1, 64); if (st < 7) incl += y1;
                float y2 = __shfl_down(incl, 2, 64); if (st < 6) incl += y2;
                float y4 = __shfl_down(incl, 4, 64); if (st < 4) incl += y4;
                float basev = (incl - total) + running;
                ushort4 wo;
                float wv;
                int jgc = j0 + st * 4;
                wv = (jgc + 0 <= ig) ? __expf(lsig[0] + suf[0] + basev) : 0.f; wo.x = f2bf(wv);
                wv = (jgc + 1 <= ig) ? __expf(lsig[1] + suf[1] + basev) : 0.f; wo.y = f2bf(wv);
                wv = (jgc + 2 <= ig) ? __expf(lsig[2] + suf[2] + basev) : 0.f; wo.z = f2bf(wv);
                wv = (jgc + 3 <= ig) ? __expf(lsig[3] + suf[3] + basev) : 0.f; wo.w = f2bf(wv);
                running += __shfl(incl, rowlane, 64);
                *(ushort4*)&wt[srow * 40 + st * 4] = wo;
            }
            __syncthreads();
            bf16x8 aw = *(const bf16x8*)&wt[(mh * 16 + lm) * 40 + g * 8];
#pragma unroll
            for (int q = 0; q < 4; q++) {
                int dt = q * 2 + dsel;
                bf16x8 bv8 = *(const bf16x8*)&Vts[(dt * 16 + lm) * 40 + g * 8];
                pacc[q] = __builtin_amdgcn_mfma_f32_16x16x32_bf16(aw, bv8, pacc[q], 0, 0, 0);
            }
        }
#pragma unroll
        for (int reg = 0; reg < 4; reg++) {
            int i = i0 + mh * 16 + g * 4 + reg;
            size_t pair = ((size_t)(b * 512 + i)) * 2 + slot;
            float gt = gates[pair];
#pragma unroll
            for (int q = 0; q < 4; q++) {
                int d = (q * 2 + dsel) * 16 + lm;
                yb[pair * 1024 + h * 128 + d] = f2bf(pacc[q][reg] * gt);
            }
        }
    }
}

// ---------------- combine pairs ----------------
__global__ __launch_bounds__(256) void combine_kernel(
    const float* __restrict__ tmp, float* __restrict__ out)
{
    int idx = blockIdx.x * 256 + threadIdx.x;
    int token = idx >> 8;
    int c4 = idx & 255;
    const float4* t4 = (const float4*)tmp;
    float4 a = t4[(size_t)(token * 2) * 256 + c4];
    float4 b = t4[(size_t)(token * 2 + 1) * 256 + c4];
    float4 r;
    r.x = a.x + b.x; r.y = a.y + b.y; r.z = a.z + b.z; r.w = a.w + b.w;
    ((float4*)out)[idx] = r;
}

extern "C" void kernel_launch(void* const* d_in, const int* in_sizes, int n_in,
                              void* d_out, int out_size, void* d_ws, size_t ws_size,
                              hipStream_t stream)
{
    const float* x     = (const float*)d_in[0];
    const float* Wg    = (const float*)d_in[1];
    const float* W_in  = (const float*)d_in[2];
    const float* W_out = (const float*)d_in[3];
    const float* Wk    = (const float*)d_in[4];
    const float* bk    = (const float*)d_in[5];
    const float* Wv    = (const float*)d_in[6];
    const float* bv    = (const float*)d_in[7];

    char* ws = (char*)d_ws;
    int*   bucket_cnt = (int*)ws;                                          // 8 i
    size_t off = 256;
    float* gates = (float*)(ws + off); off += (size_t)NPAIR * 4;           // 8 KB
    int* buckets = (int*)(ws + off);   off += (size_t)E_ * NPAIR * 4;      // 64 KB
    float* bkv   = (float*)(ws + off); off += 2048 * 4;                    // 8 KB
    float* probs = (float*)(ws + off); off += (size_t)NTOK * E_ * 4;       // 32 KB
    int*   eass  = (int*)(ws + off);   off += (size_t)NPAIR * 4;           // 8 KB
    off = (off + 255) & ~(size_t)255;
    u16* xb    = (u16*)(ws + off); off += (size_t)NTOK * C_ * 2;           // 2 MB
    u16* Wkv_t = (u16*)(ws + off); off += (size_t)2048 * 1024 * 2;         // 4 MB
    u16* wt    = (u16*)(ws + off); off += (size_t)E_ * 1024 * 1024 * 2;    // 16 MB
    u16* yb    = (u16*)(ws + off); off += (size_t)NPAIR * AH_ * 2;         // 4 MB
    u16* Qbuf  = (u16*)(ws + off); off += (size_t)32 * 512 * 128 * 2;      // 4 MB
    u16* Kbuf  = (u16*)(ws + off); off += (size_t)16 * 512 * 128 * 2;      // 2 MB
    u16* Vbuf  = (u16*)(ws + off); off += (size_t)16 * 512 * 128 * 2;      // 2 MB
    u16* Vtbuf = (u16*)(ws + off); off += (size_t)16 * 128 * 512 * 2;      // 2 MB
    float* tmp = (float*)(ws + off); off += (size_t)NPAIR * AH_ * 4;       // 8 MB

    gate_kernel<<<NTOK, 64, 0, stream>>>(x, Wg, xb, gates, probs, eass);
    route_kernel<<<1, 256, 0, stream>>>(probs, eass, bk, bv, bucket_cnt,
                                        buckets, bkv,
                                        (float*)d_out + (out_size - 1));
    transpose_cvt<<<dim3(16, 16, 8), 256, 0, stream>>>(W_in, wt);
    transpose_cvt<<<dim3(16, 16, 1), 256, 0, stream>>>(Wk, Wkv_t);
    transpose_cvt<<<dim3(16, 16, 1), 256, 0, stream>>>(Wv, Wkv_t + (size_t)1024 * 1024);

    gemm_bf16<<<dim3(8, 32), 256, 0, stream>>>(xb, Wkv_t, bkv, nullptr, nullptr,
                                               0, nullptr, Kbuf, Vbuf, 2, NTOK);
    gemm_bf16<<<dim3(E_ * 16, 16), 256, 0, stream>>>(xb, wt, nullptr, bucket_cnt,
                                                     buckets, 1, nullptr, Qbuf,
                                                     nullptr, 1, 0);
    vtrans<<<dim3(16, 2, 8), 256, 0, stream>>>(Vbuf, Vtbuf);

    attn_kernel<<<dim3(32, 8), 256, 0, stream>>>(Qbuf, Kbuf, Vtbuf, gates, yb);

    transpose_cvt<<<dim3(16, 16, 8), 256, 0, stream>>>(W_out, wt);
    gemm_bf16<<<dim3(E_ * 16, 16), 256, 0, stream>>>(yb, wt, nullptr, bucket_cnt,
                                                     buckets, 0, tmp, nullptr,
                                                     nullptr, 0, 0);

    combine_kernel<<<(NTOK * C_ / 4) / 256, 256, 0, stream>>>(tmp, (float*)d_out);
}

// Round 5
// 324.140 us; speedup vs baseline: 3.9226x; 1.0279x over previous
//
#include <hip/hip_runtime.h>
#include <cmath>

#define B_    2
#define T_    512
#define C_    1024
#define E_    8
#define NTOK  1024
#define NPAIR 2048
#define AH_   1024
#define NH_   8
#define HS_   128

typedef unsigned short u16;
typedef __attribute__((ext_vector_type(8))) short bf16x8;
typedef __attribute__((ext_vector_type(4))) float f32x4;

__device__ __forceinline__ u16 f2bf(float f) {
    union { float f; unsigned u; } v; v.f = f;
    unsigned r = v.u + 0x7fff + ((v.u >> 16) & 1);   // RNE
    return (u16)(r >> 16);
}

__device__ __forceinline__ void gload_lds16(const void* g, void* l) {
    __builtin_amdgcn_global_load_lds(
        (const __attribute__((address_space(1))) void*)g,
        (__attribute__((address_space(3))) void*)l, 16, 0, 0);
}

// ---------------- kernel 1: gate logits, top-2, x->bf16 (NO global atomics) ----------------
__global__ __launch_bounds__(64) void gate_kernel(
    const float* __restrict__ x, const float* __restrict__ Wg,
    u16* __restrict__ xb, float* __restrict__ gates,
    float* __restrict__ probs, int* __restrict__ eass)
{
    int token = blockIdx.x;
    int lane  = threadIdx.x;
    const float* xr = x + (size_t)token * C_;
    u16* xbr = xb + (size_t)token * C_;
    float acc[E_];
#pragma unroll
    for (int e = 0; e < E_; e++) acc[e] = 0.f;
    for (int c = lane; c < C_; c += 64) {
        float xv = xr[c];
        xbr[c] = f2bf(xv);
        const float* wr = Wg + c * E_;
#pragma unroll
        for (int e = 0; e < E_; e++) acc[e] += xv * wr[e];
    }
#pragma unroll
    for (int e = 0; e < E_; e++) {
        float v = acc[e];
        v += __shfl_xor(v, 32); v += __shfl_xor(v, 16); v += __shfl_xor(v, 8);
        v += __shfl_xor(v, 4);  v += __shfl_xor(v, 2);  v += __shfl_xor(v, 1);
        acc[e] = v;
    }
    if (lane == 0) {
        int i0 = 0; float v0 = acc[0];
        for (int e = 1; e < E_; e++) if (acc[e] > v0) { v0 = acc[e]; i0 = e; }
        int i1 = -1; float v1 = -3.4e38f;
        for (int e = 0; e < E_; e++) if (e != i0 && acc[e] > v1) { v1 = acc[e]; i1 = e; }
        float e1  = __expf(v1 - v0);
        float inv = 1.f / (1.f + e1);
        gates[token * 2 + 0] = inv;
        gates[token * 2 + 1] = e1 * inv;
        float s = 0.f; float pe[E_];
        for (int e = 0; e < E_; e++) { pe[e] = __expf(acc[e] - v0); s += pe[e]; }
        float sinv = 1.f / s;
        for (int e = 0; e < E_; e++) probs[token * E_ + e] = pe[e] * sinv;
        eass[token * 2 + 0] = i0;
        eass[token * 2 + 1] = i1;
    }
}

// ---------------- kernel 1b: aux-loss reduce + bucket build (single block) ----------------
__global__ __launch_bounds__(256) void route_kernel(
    const float* __restrict__ probs, const int* __restrict__ eass,
    const float* __restrict__ bk, const float* __restrict__ bv,
    int* __restrict__ bucket_cnt, int* __restrict__ buckets,
    float* __restrict__ bkv, float* __restrict__ aux_out)
{
    __shared__ float red[256][17];
    __shared__ int lcnt[E_];
    int tid = threadIdx.x;
    for (int i = tid; i < 1024; i += 256) {
        bkv[i] = bk[i];
        bkv[i + 1024] = bv[i];
    }
    float ps[E_], fc[E_];
#pragma unroll
    for (int e = 0; e < E_; e++) { ps[e] = 0.f; fc[e] = 0.f; }
    for (int k = 0; k < 4; k++) {
        int row = tid + k * 256;
#pragma unroll
        for (int e = 0; e < E_; e++) ps[e] += probs[row * E_ + e];
    }
    for (int k = 0; k < 8; k++) {
        int i = tid + k * 256;
        int ea = eass[i];
#pragma unroll
        for (int e = 0; e < E_; e++) fc[e] += (ea == e) ? 1.f : 0.f;
    }
#pragma unroll
    for (int e = 0; e < E_; e++) { red[tid][e] = ps[e]; red[tid][8 + e] = fc[e]; }
    if (tid < E_) lcnt[tid] = 0;
    __syncthreads();
    for (int s = 128; s > 0; s >>= 1) {
        if (tid < s)
#pragma unroll
            for (int j = 0; j < 16; j++) red[tid][j] += red[tid + s][j];
        __syncthreads();
    }
    if (tid == 0) {
        float s = 0.f;
        for (int e = 0; e < E_; e++)
            s += (red[0][e] * (1.f / 1024.f)) * (red[0][8 + e] * (1.f / 1024.f));
        aux_out[0] = (float)E_ * s;
    }
    for (int k = 0; k < 8; k++) {
        int i = tid + k * 256;
        int ea = eass[i];
        int pos = atomicAdd(&lcnt[ea], 1);
        buckets[ea * NPAIR + pos] = i;
    }
    __syncthreads();
    if (tid < E_) bucket_cnt[tid] = lcnt[tid];
}

// ---------------- transpose+convert 1024x1024 fp32 -> bf16 [n][k] ----------------
__global__ __launch_bounds__(256) void transpose_cvt(
    const float* __restrict__ src, u16* __restrict__ dst)
{
    __shared__ float t[64][65];
    size_t mb = (size_t)blockIdx.z << 20;
    src += mb; dst += mb;
    int r0 = blockIdx.y * 64, c0 = blockIdx.x * 64;
    int tid = threadIdx.x;
#pragma unroll
    for (int p = 0; p < 4; p++) {
        int e4 = tid + 256 * p;
        int r = e4 >> 4, c4 = e4 & 15;
        float4 v = *(const float4*)&src[(size_t)(r0 + r) * 1024 + c0 + c4 * 4];
        t[r][c4 * 4 + 0] = v.x; t[r][c4 * 4 + 1] = v.y;
        t[r][c4 * 4 + 2] = v.z; t[r][c4 * 4 + 3] = v.w;
    }
    __syncthreads();
#pragma unroll
    for (int p = 0; p < 16; p++) {
        int e = tid + 256 * p;
        int r = e >> 6, c = e & 63;
        dst[(size_t)(c0 + r) * 1024 + r0 + c] = f2bf(t[c][r]);
    }
}

// ---------------- pipelined MFMA mainloop (4-stage, depth-3 prefetch) ----------------
// K=1024, BK=32 -> 32 k-steps. Raw s_barrier + manual vmcnt: queue never drained.
__device__ __forceinline__ void mfma_mainloop(
    const u16* __restrict__ gA0, const u16* __restrict__ gA1,
    const u16* __restrict__ gB,
    u16* AsBase, u16* BsBase, int w,
    const int offA[2], const int offB[4], f32x4 acc[2][4])
{
#define ISSUE(s) { int buf_ = (s) & 3;                                         \
    gload_lds16(gA0 + (s) * 32, AsBase + buf_ * 4096 + w * 512);               \
    gload_lds16(gA1 + (s) * 32, AsBase + buf_ * 4096 + 2048 + w * 512);        \
    gload_lds16(gB  + (s) * 32, BsBase + buf_ * 2048 + w * 512); }
    ISSUE(0); ISSUE(1); ISSUE(2);
    for (int k = 0; k < 32; k++) {
        if (k < 30)       asm volatile("s_waitcnt vmcnt(6)" ::: "memory");
        else if (k == 30) asm volatile("s_waitcnt vmcnt(3)" ::: "memory");
        else              asm volatile("s_waitcnt vmcnt(0)" ::: "memory");
        __builtin_amdgcn_s_barrier();   // all waves' stage-k data in LDS; stage k-1 reads retired
        asm volatile("" ::: "memory");
        if (k < 29) ISSUE(k + 3);       // overwrites buffer (k-1)&3 — free per barrier above
        const u16* As = AsBase + (k & 3) * 4096;
        const u16* Bs = BsBase + (k & 3) * 2048;
        bf16x8 af[2], bfr[4];
#pragma unroll
        for (int i = 0; i < 2; i++) af[i] = *(const bf16x8*)&As[offA[i]];
#pragma unroll
        for (int j = 0; j < 4; j++) bfr[j] = *(const bf16x8*)&Bs[offB[j]];
#pragma unroll
        for (int i = 0; i < 2; i++)
#pragma unroll
            for (int j = 0; j < 4; j++)
                acc[i][j] = __builtin_amdgcn_mfma_f32_16x16x32_bf16(
                    af[i], bfr[j], acc[i][j], 0, 0, 0);
        asm volatile("" ::: "memory");
    }
#undef ISSUE
}

// ---------------- fused KV (dense) + q (routed) GEMM, pipelined ----------------
// bx < 256: KV  (mt=bx&7, nt=bx>>3, N=2048)  -> Kb/Vb attention layout (+bias)
// bx >= 256: q  (b2=bx-256: e=(b2>>4)&7, mt=b2&15, nt=b2>>7) -> Qb layout
__global__ __launch_bounds__(256) void gemm_fused(
    const u16* __restrict__ xb, const u16* __restrict__ Wkv_t,
    const float* __restrict__ bkv, const u16* __restrict__ Wint,
    const int* __restrict__ bucket_cnt, const int* __restrict__ buckets,
    u16* __restrict__ Kb, u16* __restrict__ Vb, u16* __restrict__ Qb)
{
    __shared__ __align__(16) u16 As[4 * 4096];
    __shared__ __align__(16) u16 Bs[4 * 2048];
    __shared__ int rowArr[128];
    int bx = blockIdx.x;
    int tid = threadIdx.x;
    bool isKV = bx < 256;
    int e, mt, nt, cnt, rowshift;
    const u16* Wt;
    if (isKV) {
        mt = bx & 7; nt = bx >> 3; cnt = NTOK; rowshift = 0; Wt = Wkv_t; e = 0;
    } else {
        int b2 = bx - 256;
        e = (b2 >> 4) & 7; mt = b2 & 15; nt = b2 >> 7;
        cnt = bucket_cnt[e]; rowshift = 1;
        Wt = Wint + ((size_t)e << 20);
    }
    int m0 = mt * 128;
    if (m0 >= cnt) return;
    int cl = min(cnt - m0, 128);
    if (tid < 128) {
        int idx = m0 + tid;
        rowArr[tid] = isKV ? idx : buckets[e * NPAIR + (idx < cnt ? idx : cnt - 1)];
    }
    __syncthreads();

    int r0 = tid >> 2, p0 = tid & 3;
    int g0 = (p0 - ((r0 >> 1) & 3)) & 3;
    const u16* gA0 = xb + (size_t)(rowArr[r0] >> rowshift) * 1024 + g0 * 8;
    const u16* gA1 = xb + (size_t)(rowArr[r0 + 64] >> rowshift) * 1024 + g0 * 8;
    const u16* gB  = Wt + (size_t)nt * 64 * 1024 + (size_t)r0 * 1024 + g0 * 8;

    int w = tid >> 6, lane = tid & 63, lm = lane & 15, g = lane >> 4;
    int offA[2], offB[4];
#pragma unroll
    for (int i = 0; i < 2; i++) {
        int m = w * 32 + i * 16 + lm;
        offA[i] = m * 32 + (((g + ((m >> 1) & 3)) & 3) << 3);
    }
#pragma unroll
    for (int j = 0; j < 4; j++) {
        int n = j * 16 + lm;
        offB[j] = n * 32 + (((g + ((n >> 1) & 3)) & 3) << 3);
    }
    f32x4 acc[2][4];
#pragma unroll
    for (int i = 0; i < 2; i++)
#pragma unroll
        for (int j = 0; j < 4; j++) acc[i][j] = 0;

    mfma_mainloop(gA0, gA1, gB, As, Bs, w, offA, offB, acc);

#pragma unroll
    for (int i = 0; i < 2; i++) {
#pragma unroll
        for (int reg = 0; reg < 4; reg++) {
            int lrow = w * 32 + i * 16 + g * 4 + reg;
            if (lrow < cl) {
                int orow = rowArr[lrow];
#pragma unroll
                for (int j = 0; j < 4; j++) {
                    int col = nt * 64 + j * 16 + lm;
                    float v = acc[i][j][reg];
                    if (isKV) {
                        v += bkv[col];
                        int tb = orow >> 9, tj = orow & 511;
                        int cc = col & 1023;
                        int hh = cc >> 7, dd = cc & 127;
                        u16* dst = (col < 1024) ? Kb : Vb;
                        dst[(((size_t)(tb * 8 + hh) * 512 + tj) << 7) + dd] = f2bf(v);
                    } else {
                        int pb = orow >> 10, pi = (orow >> 1) & 511, ps = orow & 1;
                        int hh = col >> 7, dd = col & 127;
                        Qb[((((size_t)(pb * 16 + ps * 8 + hh)) * 512 + pi) << 7) + dd] = f2bf(v);
                    }
                }
            }
        }
    }
}

// ---------------- W_out routed GEMM, pipelined, fp32 out ----------------
// flattened grid 2048: e=(bx>>4)&7, mt=bx&15, nt=bx>>7
__global__ __launch_bounds__(256) void gemm_wout(
    const u16* __restrict__ yb, const u16* __restrict__ Woutt,
    const int* __restrict__ bucket_cnt, const int* __restrict__ buckets,
    float* __restrict__ Out)
{
    __shared__ __align__(16) u16 As[4 * 4096];
    __shared__ __align__(16) u16 Bs[4 * 2048];
    __shared__ int rowArr[128];
    int bx = blockIdx.x;
    int tid = threadIdx.x;
    int e = (bx >> 4) & 7, mt = bx & 15, nt = bx >> 7;
    int cnt = bucket_cnt[e];
    int m0 = mt * 128;
    if (m0 >= cnt) return;
    int cl = min(cnt - m0, 128);
    if (tid < 128) {
        int idx = m0 + tid;
        rowArr[tid] = buckets[e * NPAIR + (idx < cnt ? idx : cnt - 1)];
    }
    __syncthreads();

    int r0 = tid >> 2, p0 = tid & 3;
    int g0 = (p0 - ((r0 >> 1) & 3)) & 3;
    const u16* gA0 = yb + (size_t)rowArr[r0] * 1024 + g0 * 8;
    const u16* gA1 = yb + (size_t)rowArr[r0 + 64] * 1024 + g0 * 8;
    const u16* gB  = Woutt + ((size_t)e << 20) + (size_t)nt * 64 * 1024
                     + (size_t)r0 * 1024 + g0 * 8;

    int w = tid >> 6, lane = tid & 63, lm = lane & 15, g = lane >> 4;
    int offA[2], offB[4];
#pragma unroll
    for (int i = 0; i < 2; i++) {
        int m = w * 32 + i * 16 + lm;
        offA[i] = m * 32 + (((g + ((m >> 1) & 3)) & 3) << 3);
    }
#pragma unroll
    for (int j = 0; j < 4; j++) {
        int n = j * 16 + lm;
        offB[j] = n * 32 + (((g + ((n >> 1) & 3)) & 3) << 3);
    }
    f32x4 acc[2][4];
#pragma unroll
    for (int i = 0; i < 2; i++)
#pragma unroll
        for (int j = 0; j < 4; j++) acc[i][j] = 0;

    mfma_mainloop(gA0, gA1, gB, As, Bs, w, offA, offB, acc);

#pragma unroll
    for (int i = 0; i < 2; i++) {
#pragma unroll
        for (int reg = 0; reg < 4; reg++) {
            int lrow = w * 32 + i * 16 + g * 4 + reg;
            if (lrow < cl) {
                int orow = rowArr[lrow];
#pragma unroll
                for (int j = 0; j < 4; j++) {
                    int col = nt * 64 + j * 16 + lm;
                    Out[(size_t)orow * 1024 + col] = acc[i][j][reg];
                }
            }
        }
    }
}

// ---------------- Vb [bh][j][d] -> Vtb [bh][d][j] (bf16 transpose) ----------------
__global__ __launch_bounds__(256) void vtrans(
    const u16* __restrict__ Vb, u16* __restrict__ Vtb)
{
    __shared__ u16 t[64][72];
    int bh = blockIdx.x;
    int d0 = blockIdx.y * 64;
    int j0 = blockIdx.z * 64;
    int tid = threadIdx.x;
#pragma unroll
    for (int p = 0; p < 2; p++) {
        int c = tid + 256 * p;
        int jr = c >> 3, c8 = c & 7;
        *(bf16x8*)&t[jr][c8 * 8] =
            *(const bf16x8*)&Vb[((size_t)bh * 512 + j0 + jr) * 128 + d0 + c8 * 8];
    }
    __syncthreads();
#pragma unroll
    for (int p = 0; p < 2; p++) {
        int c = tid + 256 * p;
        int dr = c >> 3, j8 = c & 7;
        bf16x8 o;
#pragma unroll
        for (int k = 0; k < 8; k++) o[k] = (short)t[j8 * 8 + k][dr];
        *(bf16x8*)&Vtb[((size_t)bh * 128 + d0 + dr) * 512 + j0 + j8 * 8] = o;
    }
}

// ---------------- stick-breaking flash attention, MFMA ----------------
__global__ __launch_bounds__(256) void attn_kernel(
    const u16* __restrict__ Qb, const u16* __restrict__ Kb,
    const u16* __restrict__ Vtb, const float* __restrict__ gates,
    u16* __restrict__ yb)
{
    __shared__ __align__(16) u16 Qs[32 * 136];
    __shared__ __align__(16) u16 Ks[32 * 136];
    __shared__ __align__(16) u16 Vts[128 * 40];
    __shared__ __align__(16) float sw[32 * 36];
    __shared__ __align__(16) u16 wt[32 * 40];

    int combo = blockIdx.x;
    int b = combo >> 4, slot = (combo >> 3) & 1, h = combo & 7;
    int bh = b * 8 + h;
    const u16* Qbase = Qb  + ((size_t)combo << 16);
    const u16* Kbase = Kb  + ((size_t)bh << 16);
    const u16* Vbase = Vtb + ((size_t)bh << 16);

    int tid = threadIdx.x;
    int w = tid >> 6, lane = tid & 63, lm = lane & 15, g = lane >> 4;
    int mh = w >> 1, nh = w & 1, dsel = w & 1;
    int srow = tid >> 3, st = tid & 7;
    int rowlane = lane & 56;
    const float SCALE = 0.08838834764831845f;

    for (int seg = 0; seg < 2; seg++) {
        int it = seg ? (15 - blockIdx.y) : blockIdx.y;
        int i0 = it * 32;
        __syncthreads();
#pragma unroll
        for (int p = 0; p < 2; p++) {
            int c = tid + 256 * p;
            int r = c >> 4, c8 = c & 15;
            *(bf16x8*)&Qs[r * 136 + c8 * 8] =
                *(const bf16x8*)&Qbase[(size_t)(i0 + r) * 128 + c8 * 8];
        }
        f32x4 pacc[4];
#pragma unroll
        for (int q = 0; q < 4; q++) pacc[q] = 0;
        float running = 0.f;

        for (int jt = it; jt >= 0; jt--) {
            int j0 = jt * 32;
            __syncthreads();
#pragma unroll
            for (int p = 0; p < 2; p++) {
                int c = tid + 256 * p;
                int r = c >> 4, c8 = c & 15;
                *(bf16x8*)&Ks[r * 136 + c8 * 8] =
                    *(const bf16x8*)&Kbase[(size_t)(j0 + r) * 128 + c8 * 8];
            }
#pragma unroll
            for (int p = 0; p < 2; p++) {
                int c = tid + 256 * p;
                int d = c >> 2, j8 = c & 3;
                *(bf16x8*)&Vts[d * 40 + j8 * 8] =
                    *(const bf16x8*)&Vbase[(size_t)d * 512 + j0 + j8 * 8];
            }
            __syncthreads();
            f32x4 sacc = 0;
#pragma unroll
            for (int ks = 0; ks < 4; ks++) {
                bf16x8 aq = *(const bf16x8*)&Qs[(mh * 16 + lm) * 136 + ks * 32 + g * 8];
                bf16x8 bk = *(const bf16x8*)&Ks[(nh * 16 + lm) * 136 + ks * 32 + g * 8];
                sacc = __builtin_amdgcn_mfma_f32_16x16x32_bf16(aq, bk, sacc, 0, 0, 0);
            }
#pragma unroll
            for (int reg = 0; reg < 4; reg++)
                sw[(mh * 16 + g * 4 + reg) * 36 + nh * 16 + lm] = sacc[reg] * SCALE;
            __syncthreads();
            {
                float4 sv = *(const float4*)&sw[srow * 36 + st * 4];
                float sarr[4] = {sv.x, sv.y, sv.z, sv.w};
                int ig = i0 + srow;
                float lsig[4], lb[4];
#pragma unroll
                for (int c2 = 0; c2 < 4; c2++) {
                    int jg = j0 + st * 4 + c2;
                    float sc = sarr[c2];
                    float a  = fabsf(sc);
                    float tl = log1pf(__expf(-a));
                    lsig[c2] = (sc >= 0.f) ? -tl : sc - tl;
                    lb[c2]   = (jg <= ig) ? -(tl + fmaxf(sc, 0.f)) : 0.f;
                }
                float suf[4];
                suf[3] = 0.f;
                suf[2] = lb[3];
                suf[1] = lb[2] + lb[3];
                suf[0] = lb[1] + suf[1];
                float total = lb[0] + suf[0];
                float incl = total;
                float y1 = __shfl_down(incl, 1, 64); if (st < 7) incl += y1;
                float y2 = __shfl_down(incl, 2, 64); if (st < 6) incl += y2;
                float y4 = __shfl_down(incl, 4, 64); if (st < 4) incl += y4;
                float basev = (incl - total) + running;
                ushort4 wo;
                float wv;
                int jgc = j0 + st * 4;
                wv = (jgc + 0 <= ig) ? __expf(lsig[0] + suf[0] + basev) : 0.f; wo.x = f2bf(wv);
                wv = (jgc + 1 <= ig) ? __expf(lsig[1] + suf[1] + basev) : 0.f; wo.y = f2bf(wv);
                wv = (jgc + 2 <= ig) ? __expf(lsig[2] + suf[2] + basev) : 0.f; wo.z = f2bf(wv);
                wv = (jgc + 3 <= ig) ? __expf(lsig[3] + suf[3] + basev) : 0.f; wo.w = f2bf(wv);
                running += __shfl(incl, rowlane, 64);
                *(ushort4*)&wt[srow * 40 + st * 4] = wo;
            }
            __syncthreads();
            bf16x8 aw = *(const bf16x8*)&wt[(mh * 16 + lm) * 40 + g * 8];
#pragma unroll
            for (int q = 0; q < 4; q++) {
                int dt = q * 2 + dsel;
                bf16x8 bv8 = *(const bf16x8*)&Vts[(dt * 16 + lm) * 40 + g * 8];
                pacc[q] = __builtin_amdgcn_mfma_f32_16x16x32_bf16(aw, bv8, pacc[q], 0, 0, 0);
            }
        }
#pragma unroll
        for (int reg = 0; reg < 4; reg++) {
            int i = i0 + mh * 16 + g * 4 + reg;
            size_t pair = ((size_t)(b * 512 + i)) * 2 + slot;
            float gt = gates[pair];
#pragma unroll
            for (int q = 0; q < 4; q++) {
                int d = (q * 2 + dsel) * 16 + lm;
                yb[pair * 1024 + h * 128 + d] = f2bf(pacc[q][reg] * gt);
            }
        }
    }
}

// ---------------- combine pairs ----------------
__global__ __launch_bounds__(256) void combine_kernel(
    const float* __restrict__ tmp, float* __restrict__ out)
{
    int idx = blockIdx.x * 256 + threadIdx.x;
    int token = idx >> 8;
    int c4 = idx & 255;
    const float4* t4 = (const float4*)tmp;
    float4 a = t4[(size_t)(token * 2) * 256 + c4];
    float4 b = t4[(size_t)(token * 2 + 1) * 256 + c4];
    float4 r;
    r.x = a.x + b.x; r.y = a.y + b.y; r.z = a.z + b.z; r.w = a.w + b.w;
    ((float4*)out)[idx] = r;
}

extern "C" void kernel_launch(void* const* d_in, const int* in_sizes, int n_in,
                              void* d_out, int out_size, void* d_ws, size_t ws_size,
                              hipStream_t stream)
{
    const float* x     = (const float*)d_in[0];
    const float* Wg    = (const float*)d_in[1];
    const float* W_in  = (const float*)d_in[2];
    const float* W_out = (const float*)d_in[3];
    const float* Wk    = (const float*)d_in[4];
    const float* bk    = (const float*)d_in[5];
    const float* Wv    = (const float*)d_in[6];
    const float* bv    = (const float*)d_in[7];

    char* ws = (char*)d_ws;
    int*   bucket_cnt = (int*)ws;
    size_t off = 256;
    float* gates = (float*)(ws + off); off += (size_t)NPAIR * 4;
    int* buckets = (int*)(ws + off);   off += (size_t)E_ * NPAIR * 4;
    float* bkv   = (float*)(ws + off); off += 2048 * 4;
    float* probs = (float*)(ws + off); off += (size_t)NTOK * E_ * 4;
    int*   eass  = (int*)(ws + off);   off += (size_t)NPAIR * 4;
    off = (off + 255) & ~(size_t)255;
    u16* xb    = (u16*)(ws + off); off += (size_t)NTOK * C_ * 2;
    u16* Wkv_t = (u16*)(ws + off); off += (size_t)2048 * 1024 * 2;
    u16* wt    = (u16*)(ws + off); off += (size_t)E_ * 1024 * 1024 * 2;
    u16* yb    = (u16*)(ws + off); off += (size_t)NPAIR * AH_ * 2;
    u16* Qbuf  = (u16*)(ws + off); off += (size_t)32 * 512 * 128 * 2;
    u16* Kbuf  = (u16*)(ws + off); off += (size_t)16 * 512 * 128 * 2;
    u16* Vbuf  = (u16*)(ws + off); off += (size_t)16 * 512 * 128 * 2;
    u16* Vtbuf = (u16*)(ws + off); off += (size_t)16 * 128 * 512 * 2;
    float* tmp = (float*)(ws + off); off += (size_t)NPAIR * AH_ * 4;

    gate_kernel<<<NTOK, 64, 0, stream>>>(x, Wg, xb, gates, probs, eass);
    route_kernel<<<1, 256, 0, stream>>>(probs, eass, bk, bv, bucket_cnt,
                                        buckets, bkv,
                                        (float*)d_out + (out_size - 1));
    transpose_cvt<<<dim3(16, 16, 8), 256, 0, stream>>>(W_in, wt);
    transpose_cvt<<<dim3(16, 16, 1), 256, 0, stream>>>(Wk, Wkv_t);
    transpose_cvt<<<dim3(16, 16, 1), 256, 0, stream>>>(Wv, Wkv_t + (size_t)1024 * 1024);

    // fused KV (dense, 256 blocks) + q (routed, 2048 logical blocks)
    gemm_fused<<<256 + 2048, 256, 0, stream>>>(xb, Wkv_t, bkv, wt, bucket_cnt,
                                               buckets, Kbuf, Vbuf, Qbuf);
    vtrans<<<dim3(16, 2, 8), 256, 0, stream>>>(Vbuf, Vtbuf);

    attn_kernel<<<dim3(32, 8), 256, 0, stream>>>(Qbuf, Kbuf, Vtbuf, gates, yb);

    transpose_cvt<<<dim3(16, 16, 8), 256, 0, stream>>>(W_out, wt);
    gemm_wout<<<2048, 256, 0, stream>>>(yb, wt, bucket_cnt, buckets, tmp);

    combine_kernel<<<(NTOK * C_ / 4) / 256, 256, 0, stream>>>(tmp, (float*)d_out);
}

// Round 6
// 318.165 us; speedup vs baseline: 3.9962x; 1.0188x over previous
//
#include <hip/hip_runtime.h>
#include <cmath>

#define B_    2
#define T_    512
#define C_    1024
#define E_    8
#define NTOK  1024
#define NPAIR 2048
#define AH_   1024
#define NH_   8
#define HS_   128

typedef unsigned short u16;
typedef __attribute__((ext_vector_type(8))) short bf16x8;
typedef __attribute__((ext_vector_type(4))) float f32x4;

__device__ __forceinline__ u16 f2bf(float f) {
    union { float f; unsigned u; } v; v.f = f;
    unsigned r = v.u + 0x7fff + ((v.u >> 16) & 1);   // RNE
    return (u16)(r >> 16);
}

__device__ __forceinline__ void gload_lds16(const void* g, void* l) {
    __builtin_amdgcn_global_load_lds(
        (const __attribute__((address_space(1))) void*)g,
        (__attribute__((address_space(3))) void*)l, 16, 0, 0);
}

// ---------------- kernel 1: gate logits, top-2, x->bf16 (NO global atomics) ----------------
__global__ __launch_bounds__(64) void gate_kernel(
    const float* __restrict__ x, const float* __restrict__ Wg,
    u16* __restrict__ xb, float* __restrict__ gates,
    float* __restrict__ probs, int* __restrict__ eass)
{
    int token = blockIdx.x;
    int lane  = threadIdx.x;
    const float* xr = x + (size_t)token * C_;
    u16* xbr = xb + (size_t)token * C_;
    float acc[E_];
#pragma unroll
    for (int e = 0; e < E_; e++) acc[e] = 0.f;
    for (int c = lane; c < C_; c += 64) {
        float xv = xr[c];
        xbr[c] = f2bf(xv);
        const float* wr = Wg + c * E_;
#pragma unroll
        for (int e = 0; e < E_; e++) acc[e] += xv * wr[e];
    }
#pragma unroll
    for (int e = 0; e < E_; e++) {
        float v = acc[e];
        v += __shfl_xor(v, 32); v += __shfl_xor(v, 16); v += __shfl_xor(v, 8);
        v += __shfl_xor(v, 4);  v += __shfl_xor(v, 2);  v += __shfl_xor(v, 1);
        acc[e] = v;
    }
    if (lane == 0) {
        int i0 = 0; float v0 = acc[0];
        for (int e = 1; e < E_; e++) if (acc[e] > v0) { v0 = acc[e]; i0 = e; }
        int i1 = -1; float v1 = -3.4e38f;
        for (int e = 0; e < E_; e++) if (e != i0 && acc[e] > v1) { v1 = acc[e]; i1 = e; }
        float e1  = __expf(v1 - v0);
        float inv = 1.f / (1.f + e1);
        gates[token * 2 + 0] = inv;
        gates[token * 2 + 1] = e1 * inv;
        float s = 0.f; float pe[E_];
        for (int e = 0; e < E_; e++) { pe[e] = __expf(acc[e] - v0); s += pe[e]; }
        float sinv = 1.f / s;
        for (int e = 0; e < E_; e++) probs[token * E_ + e] = pe[e] * sinv;
        eass[token * 2 + 0] = i0;
        eass[token * 2 + 1] = i1;
    }
}

// ---------------- kernel 1b: aux-loss reduce + bucket build (single block) ----------------
__global__ __launch_bounds__(256) void route_kernel(
    const float* __restrict__ probs, const int* __restrict__ eass,
    const float* __restrict__ bk, const float* __restrict__ bv,
    int* __restrict__ bucket_cnt, int* __restrict__ buckets,
    float* __restrict__ bkv, float* __restrict__ aux_out)
{
    __shared__ float red[256][17];
    __shared__ int lcnt[E_];
    int tid = threadIdx.x;
    for (int i = tid; i < 1024; i += 256) {
        bkv[i] = bk[i];
        bkv[i + 1024] = bv[i];
    }
    float ps[E_], fc[E_];
#pragma unroll
    for (int e = 0; e < E_; e++) { ps[e] = 0.f; fc[e] = 0.f; }
    for (int k = 0; k < 4; k++) {
        int row = tid + k * 256;
#pragma unroll
        for (int e = 0; e < E_; e++) ps[e] += probs[row * E_ + e];
    }
    for (int k = 0; k < 8; k++) {
        int i = tid + k * 256;
        int ea = eass[i];
#pragma unroll
        for (int e = 0; e < E_; e++) fc[e] += (ea == e) ? 1.f : 0.f;
    }
#pragma unroll
    for (int e = 0; e < E_; e++) { red[tid][e] = ps[e]; red[tid][8 + e] = fc[e]; }
    if (tid < E_) lcnt[tid] = 0;
    __syncthreads();
    for (int s = 128; s > 0; s >>= 1) {
        if (tid < s)
#pragma unroll
            for (int j = 0; j < 16; j++) red[tid][j] += red[tid + s][j];
        __syncthreads();
    }
    if (tid == 0) {
        float s = 0.f;
        for (int e = 0; e < E_; e++)
            s += (red[0][e] * (1.f / 1024.f)) * (red[0][8 + e] * (1.f / 1024.f));
        aux_out[0] = (float)E_ * s;
    }
    for (int k = 0; k < 8; k++) {
        int i = tid + k * 256;
        int ea = eass[i];
        int pos = atomicAdd(&lcnt[ea], 1);
        buckets[ea * NPAIR + pos] = i;
    }
    __syncthreads();
    if (tid < E_) bucket_cnt[tid] = lcnt[tid];
}

// ---------------- transpose+convert 1024x1024 fp32 -> bf16 [n][k] ----------------
__global__ __launch_bounds__(256) void transpose_cvt(
    const float* __restrict__ src, u16* __restrict__ dst)
{
    __shared__ float t[64][65];
    size_t mb = (size_t)blockIdx.z << 20;
    src += mb; dst += mb;
    int r0 = blockIdx.y * 64, c0 = blockIdx.x * 64;
    int tid = threadIdx.x;
#pragma unroll
    for (int p = 0; p < 4; p++) {
        int e4 = tid + 256 * p;
        int r = e4 >> 4, c4 = e4 & 15;
        float4 v = *(const float4*)&src[(size_t)(r0 + r) * 1024 + c0 + c4 * 4];
        t[r][c4 * 4 + 0] = v.x; t[r][c4 * 4 + 1] = v.y;
        t[r][c4 * 4 + 2] = v.z; t[r][c4 * 4 + 3] = v.w;
    }
    __syncthreads();
#pragma unroll
    for (int p = 0; p < 16; p++) {
        int e = tid + 256 * p;
        int r = e >> 6, c = e & 63;
        dst[(size_t)(c0 + r) * 1024 + r0 + c] = f2bf(t[c][r]);
    }
}

// ---------------- pipelined 128x128x32 MFMA mainloop (4-stage, depth-3) ----------------
// Per step: stage A 128x32 (2 issues) + B 128x32 (2 issues), 16 MFMA/wave.
__device__ __forceinline__ void mfma_mainloop128(
    const u16* __restrict__ gA0, const u16* __restrict__ gA1,
    const u16* __restrict__ gB0, const u16* __restrict__ gB1,
    u16* AsBase, u16* BsBase, int w,
    const int offA[4], const int offB[4], f32x4 acc[4][4])
{
#define ISSUE(s) { int buf_ = (s) & 3;                                         \
    gload_lds16(gA0 + (s) * 32, AsBase + buf_ * 4096 + w * 512);               \
    gload_lds16(gA1 + (s) * 32, AsBase + buf_ * 4096 + 2048 + w * 512);        \
    gload_lds16(gB0 + (s) * 32, BsBase + buf_ * 4096 + w * 512);               \
    gload_lds16(gB1 + (s) * 32, BsBase + buf_ * 4096 + 2048 + w * 512); }
    ISSUE(0); ISSUE(1); ISSUE(2);
    for (int k = 0; k < 32; k++) {
        if (k < 30)       asm volatile("s_waitcnt vmcnt(8)" ::: "memory");
        else if (k == 30) asm volatile("s_waitcnt vmcnt(4)" ::: "memory");
        else              asm volatile("s_waitcnt vmcnt(0)" ::: "memory");
        __builtin_amdgcn_s_barrier();   // stage-k data in LDS for all waves
        asm volatile("" ::: "memory");
        if (k < 29) ISSUE(k + 3);       // overwrites buffer (k-1)&3 — retired per barrier
        const u16* As = AsBase + (k & 3) * 4096;
        const u16* Bs = BsBase + (k & 3) * 4096;
        bf16x8 af[4], bfr[4];
#pragma unroll
        for (int i = 0; i < 4; i++) af[i] = *(const bf16x8*)&As[offA[i]];
#pragma unroll
        for (int j = 0; j < 4; j++) bfr[j] = *(const bf16x8*)&Bs[offB[j]];
#pragma unroll
        for (int i = 0; i < 4; i++)
#pragma unroll
            for (int j = 0; j < 4; j++)
                acc[i][j] = __builtin_amdgcn_mfma_f32_16x16x32_bf16(
                    af[i], bfr[j], acc[i][j], 0, 0, 0);
        asm volatile("" ::: "memory");
    }
#undef ISSUE
}

__device__ __forceinline__ void frag_offsets(int base, int lm, int g, int off[4])
{
#pragma unroll
    for (int i = 0; i < 4; i++) {
        int m = base + i * 16 + lm;
        off[i] = m * 32 + (((g + ((m >> 1) & 3)) & 3) << 3);
    }
}

// ---------------- fused KV (dense) + q (routed) GEMM, 128x128, pipelined ----------------
// bx < 128: KV  (mt=bx&7, nt=bx>>3, N=2048)  -> Kb/Vb attention layout (+bias)
// bx >= 128: q  (b2: e=(b2>>4)&7, mt=b2&15, nt=b2>>7) -> Qb layout
__global__ __launch_bounds__(256, 2) void gemm_fused(
    const u16* __restrict__ xb, const u16* __restrict__ Wkv_t,
    const float* __restrict__ bkv, const u16* __restrict__ Wint,
    const int* __restrict__ bucket_cnt, const int* __restrict__ buckets,
    u16* __restrict__ Kb, u16* __restrict__ Vb, u16* __restrict__ Qb)
{
    __shared__ __align__(16) u16 As[4 * 4096];
    __shared__ __align__(16) u16 Bs[4 * 4096];
    __shared__ int rowArr[128];
    int bx = blockIdx.x;
    int tid = threadIdx.x;
    bool isKV = bx < 128;
    int e, mt, nt, cnt, rowshift;
    const u16* Wt;
    if (isKV) {
        mt = bx & 7; nt = bx >> 3; cnt = NTOK; rowshift = 0; Wt = Wkv_t; e = 0;
    } else {
        int b2 = bx - 128;
        e = (b2 >> 4) & 7; mt = b2 & 15; nt = b2 >> 7;
        cnt = bucket_cnt[e]; rowshift = 1;
        Wt = Wint + ((size_t)e << 20);
    }
    int m0 = mt * 128;
    if (m0 >= cnt) return;
    int cl = min(cnt - m0, 128);
    if (tid < 128) {
        int idx = m0 + tid;
        rowArr[tid] = isKV ? idx : buckets[e * NPAIR + (idx < cnt ? idx : cnt - 1)];
    }
    __syncthreads();

    int r0 = tid >> 2, p0 = tid & 3;
    int g0 = (p0 - ((r0 >> 1) & 3)) & 3;
    const u16* gA0 = xb + (size_t)(rowArr[r0] >> rowshift) * 1024 + g0 * 8;
    const u16* gA1 = xb + (size_t)(rowArr[r0 + 64] >> rowshift) * 1024 + g0 * 8;
    const u16* Wn  = Wt + ((size_t)nt << 17);           // nt*128*1024
    const u16* gB0 = Wn + (size_t)r0 * 1024 + g0 * 8;
    const u16* gB1 = gB0 + (size_t)64 * 1024;

    int w = tid >> 6, lane = tid & 63, lm = lane & 15, g = lane >> 4;
    int mq = w >> 1, nq = w & 1;
    int offA[4], offB[4];
    frag_offsets(mq * 64, lm, g, offA);
    frag_offsets(nq * 64, lm, g, offB);
    f32x4 acc[4][4];
#pragma unroll
    for (int i = 0; i < 4; i++)
#pragma unroll
        for (int j = 0; j < 4; j++) acc[i][j] = 0;

    mfma_mainloop128(gA0, gA1, gB0, gB1, As, Bs, w, offA, offB, acc);

#pragma unroll
    for (int i = 0; i < 4; i++) {
#pragma unroll
        for (int reg = 0; reg < 4; reg++) {
            int lrow = mq * 64 + i * 16 + g * 4 + reg;
            if (lrow < cl) {
                int orow = rowArr[lrow];
#pragma unroll
                for (int j = 0; j < 4; j++) {
                    int col = nt * 128 + nq * 64 + j * 16 + lm;
                    float v = acc[i][j][reg];
                    if (isKV) {
                        v += bkv[col];
                        int tb = orow >> 9, tj = orow & 511;
                        int cc = col & 1023;
                        int hh = cc >> 7, dd = cc & 127;
                        u16* dst = (col < 1024) ? Kb : Vb;
                        dst[(((size_t)(tb * 8 + hh) * 512 + tj) << 7) + dd] = f2bf(v);
                    } else {
                        int pb = orow >> 10, pi = (orow >> 1) & 511, ps = orow & 1;
                        int hh = col >> 7, dd = col & 127;
                        Qb[((((size_t)(pb * 16 + ps * 8 + hh)) * 512 + pi) << 7) + dd] = f2bf(v);
                    }
                }
            }
        }
    }
}

// ---------------- W_out routed GEMM, 128x128, pipelined, fp32 out ----------------
// grid 1024: e=(bx>>4)&7, mt=bx&15, nt=bx>>7
__global__ __launch_bounds__(256, 2) void gemm_wout(
    const u16* __restrict__ yb, const u16* __restrict__ Woutt,
    const int* __restrict__ bucket_cnt, const int* __restrict__ buckets,
    float* __restrict__ Out)
{
    __shared__ __align__(16) u16 As[4 * 4096];
    __shared__ __align__(16) u16 Bs[4 * 4096];
    __shared__ int rowArr[128];
    int bx = blockIdx.x;
    int tid = threadIdx.x;
    int e = (bx >> 4) & 7, mt = bx & 15, nt = bx >> 7;
    int cnt = bucket_cnt[e];
    int m0 = mt * 128;
    if (m0 >= cnt) return;
    int cl = min(cnt - m0, 128);
    if (tid < 128) {
        int idx = m0 + tid;
        rowArr[tid] = buckets[e * NPAIR + (idx < cnt ? idx : cnt - 1)];
    }
    __syncthreads();

    int r0 = tid >> 2, p0 = tid & 3;
    int g0 = (p0 - ((r0 >> 1) & 3)) & 3;
    const u16* gA0 = yb + (size_t)rowArr[r0] * 1024 + g0 * 8;
    const u16* gA1 = yb + (size_t)rowArr[r0 + 64] * 1024 + g0 * 8;
    const u16* Wn  = Woutt + ((size_t)e << 20) + ((size_t)nt << 17);
    const u16* gB0 = Wn + (size_t)r0 * 1024 + g0 * 8;
    const u16* gB1 = gB0 + (size_t)64 * 1024;

    int w = tid >> 6, lane = tid & 63, lm = lane & 15, g = lane >> 4;
    int mq = w >> 1, nq = w & 1;
    int offA[4], offB[4];
    frag_offsets(mq * 64, lm, g, offA);
    frag_offsets(nq * 64, lm, g, offB);
    f32x4 acc[4][4];
#pragma unroll
    for (int i = 0; i < 4; i++)
#pragma unroll
        for (int j = 0; j < 4; j++) acc[i][j] = 0;

    mfma_mainloop128(gA0, gA1, gB0, gB1, As, Bs, w, offA, offB, acc);

#pragma unroll
    for (int i = 0; i < 4; i++) {
#pragma unroll
        for (int reg = 0; reg < 4; reg++) {
            int lrow = mq * 64 + i * 16 + g * 4 + reg;
            if (lrow < cl) {
                int orow = rowArr[lrow];
#pragma unroll
                for (int j = 0; j < 4; j++) {
                    int col = nt * 128 + nq * 64 + j * 16 + lm;
                    Out[(size_t)orow * 1024 + col] = acc[i][j][reg];
                }
            }
        }
    }
}

// ---------------- Vb [bh][j][d] -> Vtb [bh][d][j] (bf16 transpose) ----------------
__global__ __launch_bounds__(256) void vtrans(
    const u16* __restrict__ Vb, u16* __restrict__ Vtb)
{
    __shared__ u16 t[64][72];
    int bh = blockIdx.x;
    int d0 = blockIdx.y * 64;
    int j0 = blockIdx.z * 64;
    int tid = threadIdx.x;
#pragma unroll
    for (int p = 0; p < 2; p++) {
        int c = tid + 256 * p;
        int jr = c >> 3, c8 = c & 7;
        *(bf16x8*)&t[jr][c8 * 8] =
            *(const bf16x8*)&Vb[((size_t)bh * 512 + j0 + jr) * 128 + d0 + c8 * 8];
    }
    __syncthreads();
#pragma unroll
    for (int p = 0; p < 2; p++) {
        int c = tid + 256 * p;
        int dr = c >> 3, j8 = c & 7;
        bf16x8 o;
#pragma unroll
        for (int k = 0; k < 8; k++) o[k] = (short)t[j8 * 8 + k][dr];
        *(bf16x8*)&Vtb[((size_t)bh * 128 + d0 + dr) * 512 + j0 + j8 * 8] = o;
    }
}

// ---------------- stick-breaking flash attention, MFMA ----------------
__global__ __launch_bounds__(256) void attn_kernel(
    const u16* __restrict__ Qb, const u16* __restrict__ Kb,
    const u16* __restrict__ Vtb, const float* __restrict__ gates,
    u16* __restrict__ yb)
{
    __shared__ __align__(16) u16 Qs[32 * 136];
    __shared__ __align__(16) u16 Ks[32 * 136];
    __shared__ __align__(16) u16 Vts[128 * 40];
    __shared__ __align__(16) float sw[32 * 36];
    __shared__ __align__(16) u16 wt[32 * 40];

    int combo = blockIdx.x;
    int b = combo >> 4, slot = (combo >> 3) & 1, h = combo & 7;
    int bh = b * 8 + h;
    const u16* Qbase = Qb  + ((size_t)combo << 16);
    const u16* Kbase = Kb  + ((size_t)bh << 16);
    const u16* Vbase = Vtb + ((size_t)bh << 16);

    int tid = threadIdx.x;
    int w = tid >> 6, lane = tid & 63, lm = lane & 15, g = lane >> 4;
    int mh = w >> 1, nh = w & 1, dsel = w & 1;
    int srow = tid >> 3, st = tid & 7;
    int rowlane = lane & 56;
    const float SCALE = 0.08838834764831845f;

    for (int seg = 0; seg < 2; seg++) {
        int it = seg ? (15 - blockIdx.y) : blockIdx.y;
        int i0 = it * 32;
        __syncthreads();
#pragma unroll
        for (int p = 0; p < 2; p++) {
            int c = tid + 256 * p;
            int r = c >> 4, c8 = c & 15;
            *(bf16x8*)&Qs[r * 136 + c8 * 8] =
                *(const bf16x8*)&Qbase[(size_t)(i0 + r) * 128 + c8 * 8];
        }
        f32x4 pacc[4];
#pragma unroll
        for (int q = 0; q < 4; q++) pacc[q] = 0;
        float running = 0.f;

        for (int jt = it; jt >= 0; jt--) {
            int j0 = jt * 32;
            __syncthreads();
#pragma unroll
            for (int p = 0; p < 2; p++) {
                int c = tid + 256 * p;
                int r = c >> 4, c8 = c & 15;
                *(bf16x8*)&Ks[r * 136 + c8 * 8] =
                    *(const bf16x8*)&Kbase[(size_t)(j0 + r) * 128 + c8 * 8];
            }
#pragma unroll
            for (int p = 0; p < 2; p++) {
                int c = tid + 256 * p;
                int d = c >> 2, j8 = c & 3;
                *(bf16x8*)&Vts[d * 40 + j8 * 8] =
                    *(const bf16x8*)&Vbase[(size_t)d * 512 + j0 + j8 * 8];
            }
            __syncthreads();
            f32x4 sacc = 0;
#pragma unroll
            for (int ks = 0; ks < 4; ks++) {
                bf16x8 aq = *(const bf16x8*)&Qs[(mh * 16 + lm) * 136 + ks * 32 + g * 8];
                bf16x8 bk = *(const bf16x8*)&Ks[(nh * 16 + lm) * 136 + ks * 32 + g * 8];
                sacc = __builtin_amdgcn_mfma_f32_16x16x32_bf16(aq, bk, sacc, 0, 0, 0);
            }
#pragma unroll
            for (int reg = 0; reg < 4; reg++)
                sw[(mh * 16 + g * 4 + reg) * 36 + nh * 16 + lm] = sacc[reg] * SCALE;
            __syncthreads();
            {
                float4 sv = *(const float4*)&sw[srow * 36 + st * 4];
                float sarr[4] = {sv.x, sv.y, sv.z, sv.w};
                int ig = i0 + srow;
                float lsig[4], lb[4];
#pragma unroll
                for (int c2 = 0; c2 < 4; c2++) {
                    int jg = j0 + st * 4 + c2;
                    float sc = sarr[c2];
                    float a  = fabsf(sc);
                    float tl = log1pf(__expf(-a));
                    lsig[c2] = (sc >= 0.f) ? -tl : sc - tl;
                    lb[c2]   = (jg <= ig) ? -(tl + fmaxf(sc, 0.f)) : 0.f;
                }
                float suf[4];
                suf[3] = 0.f;
                suf[2] = lb[3];
                suf[1] = lb[2] + lb[3];
                suf[0] = lb[1] + suf[1];
                float total = lb[0] + suf[0];
                float incl = total;
                float y1 = __shfl_down(incl, 1, 64); if (st < 7) incl += y1;
                float y2 = __shfl_down(incl, 2, 64); if (st < 6) incl += y2;
                float y4 = __shfl_down(incl, 4, 64); if (st < 4) incl += y4;
                float basev = (incl - total) + running;
                ushort4 wo;
                float wv;
                int jgc = j0 + st * 4;
                wv = (jgc + 0 <= ig) ? __expf(lsig[0] + suf[0] + basev) : 0.f; wo.x = f2bf(wv);
                wv = (jgc + 1 <= ig) ? __expf(lsig[1] + suf[1] + basev) : 0.f; wo.y = f2bf(wv);
                wv = (jgc + 2 <= ig) ? __expf(lsig[2] + suf[2] + basev) : 0.f; wo.z = f2bf(wv);
                wv = (jgc + 3 <= ig) ? __expf(lsig[3] + suf[3] + basev) : 0.f; wo.w = f2bf(wv);
                running += __shfl(incl, rowlane, 64);
                *(ushort4*)&wt[srow * 40 + st * 4] = wo;
            }
            __syncthreads();
            bf16x8 aw = *(const bf16x8*)&wt[(mh * 16 + lm) * 40 + g * 8];
#pragma unroll
            for (int q = 0; q < 4; q++) {
                int dt = q * 2 + dsel;
                bf16x8 bv8 = *(const bf16x8*)&Vts[(dt * 16 + lm) * 40 + g * 8];
                pacc[q] = __builtin_amdgcn_mfma_f32_16x16x32_bf16(aw, bv8, pacc[q], 0, 0, 0);
            }
        }
#pragma unroll
        for (int reg = 0; reg < 4; reg++) {
            int i = i0 + mh * 16 + g * 4 + reg;
            size_t pair = ((size_t)(b * 512 + i)) * 2 + slot;
            float gt = gates[pair];
#pragma unroll
            for (int q = 0; q < 4; q++) {
                int d = (q * 2 + dsel) * 16 + lm;
                yb[pair * 1024 + h * 128 + d] = f2bf(pacc[q][reg] * gt);
            }
        }
    }
}

// ---------------- combine pairs ----------------
__global__ __launch_bounds__(256) void combine_kernel(
    const float* __restrict__ tmp, float* __restrict__ out)
{
    int idx = blockIdx.x * 256 + threadIdx.x;
    int token = idx >> 8;
    int c4 = idx & 255;
    const float4* t4 = (const float4*)tmp;
    float4 a = t4[(size_t)(token * 2) * 256 + c4];
    float4 b = t4[(size_t)(token * 2 + 1) * 256 + c4];
    float4 r;
    r.x = a.x + b.x; r.y = a.y + b.y; r.z = a.z + b.z; r.w = a.w + b.w;
    ((float4*)out)[idx] = r;
}

extern "C" void kernel_launch(void* const* d_in, const int* in_sizes, int n_in,
                              void* d_out, int out_size, void* d_ws, size_t ws_size,
                              hipStream_t stream)
{
    const float* x     = (const float*)d_in[0];
    const float* Wg    = (const float*)d_in[1];
    const float* W_in  = (const float*)d_in[2];
    const float* W_out = (const float*)d_in[3];
    const float* Wk    = (const float*)d_in[4];
    const float* bk    = (const float*)d_in[5];
    const float* Wv    = (const float*)d_in[6];
    const float* bv    = (const float*)d_in[7];

    char* ws = (char*)d_ws;
    int*   bucket_cnt = (int*)ws;
    size_t off = 256;
    float* gates = (float*)(ws + off); off += (size_t)NPAIR * 4;
    int* buckets = (int*)(ws + off);   off += (size_t)E_ * NPAIR * 4;
    float* bkv   = (float*)(ws + off); off += 2048 * 4;
    float* probs = (float*)(ws + off); off += (size_t)NTOK * E_ * 4;
    int*   eass  = (int*)(ws + off);   off += (size_t)NPAIR * 4;
    off = (off + 255) & ~(size_t)255;
    u16* xb    = (u16*)(ws + off); off += (size_t)NTOK * C_ * 2;
    u16* Wkv_t = (u16*)(ws + off); off += (size_t)2048 * 1024 * 2;
    u16* wt    = (u16*)(ws + off); off += (size_t)E_ * 1024 * 1024 * 2;
    u16* yb    = (u16*)(ws + off); off += (size_t)NPAIR * AH_ * 2;
    u16* Qbuf  = (u16*)(ws + off); off += (size_t)32 * 512 * 128 * 2;
    u16* Kbuf  = (u16*)(ws + off); off += (size_t)16 * 512 * 128 * 2;
    u16* Vbuf  = (u16*)(ws + off); off += (size_t)16 * 512 * 128 * 2;
    u16* Vtbuf = (u16*)(ws + off); off += (size_t)16 * 128 * 512 * 2;
    float* tmp = (float*)(ws + off); off += (size_t)NPAIR * AH_ * 4;

    gate_kernel<<<NTOK, 64, 0, stream>>>(x, Wg, xb, gates, probs, eass);
    route_kernel<<<1, 256, 0, stream>>>(probs, eass, bk, bv, bucket_cnt,
                                        buckets, bkv,
                                        (float*)d_out + (out_size - 1));
    transpose_cvt<<<dim3(16, 16, 8), 256, 0, stream>>>(W_in, wt);
    transpose_cvt<<<dim3(16, 16, 1), 256, 0, stream>>>(Wk, Wkv_t);
    transpose_cvt<<<dim3(16, 16, 1), 256, 0, stream>>>(Wv, Wkv_t + (size_t)1024 * 1024);

    // fused KV (dense, 128 blocks) + q (routed, 1024 logical blocks)
    gemm_fused<<<128 + 1024, 256, 0, stream>>>(xb, Wkv_t, bkv, wt, bucket_cnt,
                                               buckets, Kbuf, Vbuf, Qbuf);
    vtrans<<<dim3(16, 2, 8), 256, 0, stream>>>(Vbuf, Vtbuf);

    attn_kernel<<<dim3(32, 8), 256, 0, stream>>>(Qbuf, Kbuf, Vtbuf, gates, yb);

    transpose_cvt<<<dim3(16, 16, 8), 256, 0, stream>>>(W_out, wt);
    gemm_wout<<<1024, 256, 0, stream>>>(yb, wt, bucket_cnt, buckets, tmp);

    combine_kernel<<<(NTOK * C_ / 4) / 256, 256, 0, stream>>>(tmp, (float*)d_out);
}